// Round 16
// baseline (776.387 us; speedup 1.0000x reference)
//
#include <hip/hip_runtime.h>
#include <math.h>

#define HWD 1089
#define WD 33
#define NF 128
#define NJ 124
#define CC 32

typedef __attribute__((ext_vector_type(8))) short s16x8;
typedef __attribute__((ext_vector_type(4))) float f32x4;

__device__ __forceinline__ float sigm(float z) { return 1.f / (1.f + expf(-z)); }
__device__ __forceinline__ int sel4(int4 v, int i) { return i == 0 ? v.x : i == 1 ? v.y : i == 2 ? v.z : v.w; }
__device__ __forceinline__ short f2b(float f) {
    union { float f; unsigned u; } x; x.f = f;
    unsigned r = x.u + 0x7fffu + ((x.u >> 16) & 1u);
    return (short)(r >> 16);
}
__device__ __forceinline__ float b2f(unsigned short u) {
    union { unsigned u; float f; } x; x.u = (unsigned)u << 16;
    return x.f;
}
__device__ __forceinline__ unsigned pk2bf(float a, float b) {
    unsigned r;
    asm("v_cvt_pk_bf16_f32 %0, %1, %2" : "=v"(r) : "v"(a), "v"(b));
    return r;
}

// ---------------- rs[j] = sum_k mlp_w[j][k] ----------------
__global__ void rowsum_k(const float* __restrict__ mw, float* __restrict__ rs) {
    int j = blockIdx.x;
    const float* row = mw + (size_t)j * HWD;
    float s = 0.f;
    for (int k = threadIdx.x; k < HWD; k += 256) s += row[k];
    __shared__ float red[256];
    red[threadIdx.x] = s; __syncthreads();
    for (int off = 128; off > 0; off >>= 1) {
        if (threadIdx.x < off) red[threadIdx.x] += red[threadIdx.x + off];
        __syncthreads();
    }
    if (threadIdx.x == 0) rs[j] = red[0];
}

// ---------------- imgs = x * sigmoid((t/20)*rs + mlp_b) ----------------
__global__ void imgs_k(const float* __restrict__ x, const float* __restrict__ rs,
                       const float* __restrict__ mb, float* __restrict__ imgs) {
    int idx = blockIdx.x * 256 + threadIdx.x;
    if (idx >= NF * HWD) return;
    int t = idx / HWD, p = idx % HWD;
    float pe = sigm(((float)t / 20.0f) * rs[p] + mb[p]);
    imgs[idx] = x[idx] * pe;
}

// ---------------- weight pack: 15 tensors -> bf16 MFMA B-fragments ----------------
// t: 0=off1_w(18) 1=off2_w(18) 2..6=rb_w1[l](32) 7..11=rb_w2[l](32) 12=dw1(32) 13=dw2(32) 14=conv_w(1)
__global__ void pack_k(const float* __restrict__ off1_w, const float* __restrict__ off2_w,
                       const float* __restrict__ rb_w1, const float* __restrict__ rb_w2,
                       const float* __restrict__ dw1, const float* __restrict__ dw2,
                       const float* __restrict__ conv_w, unsigned short* __restrict__ wp) {
    int tid = blockIdx.x * 256 + threadIdx.x;
    if (tid >= 15 * 9216) return;
    int t = tid / 9216, u = tid - t * 9216;
    int j = u & 7, l = (u >> 3) & 63, h = (u >> 9) & 1, k = u >> 10;
    int o = h * 16 + (l & 15);
    int c = 8 * (l >> 4) + j;
    const float* src;
    int cout;
    if (t == 0)       { src = off1_w; cout = 18; }
    else if (t == 1)  { src = off2_w; cout = 18; }
    else if (t < 7)   { src = rb_w1 + (size_t)(t - 2) * 9216; cout = 32; }
    else if (t < 12)  { src = rb_w2 + (size_t)(t - 7) * 9216; cout = 32; }
    else if (t == 12) { src = dw1; cout = 32; }
    else if (t == 13) { src = dw2; cout = 32; }
    else              { src = conv_w; cout = 1; }
    float val = (o < cout) ? src[(o * 32 + c) * 9 + k] : 0.f;
    wp[tid] = (unsigned short)f2b(val);
}

// ---------------- MFMA 3x3 conv, bf16 NHWC input, COUT out, 9-tap prefetch ----------------
template <int COUT, bool RELU, bool HAS_RES, bool WF32, bool WBF>
__global__ __launch_bounds__(256, 2)
void mfmaconv_k(const unsigned short* __restrict__ in, const unsigned short* __restrict__ wp,
                const float* __restrict__ bias, const float* __restrict__ res,
                float* __restrict__ outf, int out_ps, unsigned short* __restrict__ outb_,
                int Npix) {
    int lane = threadIdx.x & 63;
    int wav  = threadIdx.x >> 6;
    int pix0 = (blockIdx.x * 4 + wav) * 16;
    if (pix0 >= Npix) return;
    s16x8 bf[18];
#pragma unroll
    for (int i = 0; i < 18; ++i)
        bf[i] = *(const s16x8*)(wp + ((size_t)(i * 64 + lane)) * 8);
    int am = lane & 15;
    int ak = lane >> 4;
    int apix = pix0 + am;
    bool aval = apix < Npix;
    int apixc = min(apix, Npix - 1);
    int ap = apixc % HWD;
    int ah = ap / WD, aq = ap - ah * WD;
    const unsigned short* abase = in + (size_t)apixc * 32 + ak * 8;
    s16x8 u[9];
    bool vm[9];
#pragma unroll
    for (int k = 0; k < 9; ++k) {
        int dy = k / 3 - 1, dx = k % 3 - 1;
        int hh = ah + dy, qq = aq + dx;
        vm[k] = aval && hh >= 0 && hh < WD && qq >= 0 && qq < WD;
        const unsigned short* ipp = vm[k] ? (abase + (dy * WD + dx) * 32) : abase;
        u[k] = *(const s16x8*)(ipp);
    }
    const s16x8 zz = {0, 0, 0, 0, 0, 0, 0, 0};
    f32x4 acc0 = {0.f, 0.f, 0.f, 0.f};
    f32x4 acc1 = {0.f, 0.f, 0.f, 0.f};
#pragma unroll
    for (int k = 0; k < 9; ++k) {
        s16x8 af = vm[k] ? u[k] : zz;
        acc0 = __builtin_amdgcn_mfma_f32_16x16x32_bf16(af, bf[k * 2 + 0], acc0, 0, 0, 0);
        acc1 = __builtin_amdgcn_mfma_f32_16x16x32_bf16(af, bf[k * 2 + 1], acc1, 0, 0, 0);
    }
    int n = lane & 15;
    int mrow = (lane >> 4) * 4;
    float b0 = bias[n];
    float b1 = (16 + n < COUT) ? bias[16 + n] : 0.f;
#pragma unroll
    for (int i = 0; i < 4; ++i) {
        int pix = pix0 + mrow + i;
        if (pix >= Npix) continue;
        float v0 = acc0[i] + b0;
        if (RELU) v0 = fmaxf(v0, 0.f);
        if (HAS_RES) v0 += res[(size_t)pix * 32 + n];
        if (WF32) outf[(size_t)pix * out_ps + n] = v0;
        if (WBF) outb_[(size_t)pix * 32 + n] = (unsigned short)f2b(v0);
        if (16 + n < COUT) {
            float v1 = acc1[i] + b1;
            if (RELU) v1 = fmaxf(v1, 0.f);
            if (HAS_RES) v1 += res[(size_t)pix * 32 + 16 + n];
            if (WF32) outf[(size_t)pix * out_ps + 16 + n] = v1;
            if (WBF) outb_[(size_t)pix * 32 + 16 + n] = (unsigned short)f2b(v1);
        }
    }
}

// ---------------- MFMA 3x3 conv 32->1 (bf16 in) -> aligned NCHW channel ----------------
__global__ __launch_bounds__(256, 2)
void convout_mfma_k(const unsigned short* __restrict__ in, const unsigned short* __restrict__ wp,
                    const float* __restrict__ cb, float* __restrict__ outA, int4 cidx, int Npix) {
    int lane = threadIdx.x & 63;
    int wav  = threadIdx.x >> 6;
    int pix0 = (blockIdx.x * 4 + wav) * 16;
    if (pix0 >= Npix) return;
    s16x8 bc[9];
#pragma unroll
    for (int k = 0; k < 9; ++k)
        bc[k] = *(const s16x8*)(wp + ((size_t)((k * 2 + 0) * 64 + lane)) * 8);
    int am = lane & 15, ak = lane >> 4;
    int apix = pix0 + am;
    bool aval = apix < Npix;
    int apixc = min(apix, Npix - 1);
    int ap = apixc % HWD;
    int ah = ap / WD, aq = ap - ah * WD;
    const unsigned short* abase = in + (size_t)apixc * 32 + ak * 8;
    s16x8 u[9];
    bool vm[9];
#pragma unroll
    for (int k = 0; k < 9; ++k) {
        int dy = k / 3 - 1, dx = k % 3 - 1;
        int hh = ah + dy, qq = aq + dx;
        vm[k] = aval && hh >= 0 && hh < WD && qq >= 0 && qq < WD;
        const unsigned short* ipp = vm[k] ? (abase + (dy * WD + dx) * 32) : abase;
        u[k] = *(const s16x8*)(ipp);
    }
    const s16x8 zz = {0, 0, 0, 0, 0, 0, 0, 0};
    f32x4 acc = {0.f, 0.f, 0.f, 0.f};
#pragma unroll
    for (int k = 0; k < 9; ++k)
        acc = __builtin_amdgcn_mfma_f32_16x16x32_bf16(vm[k] ? u[k] : zz, bc[k], acc, 0, 0, 0);
    if ((lane & 15) == 0) {
        float b0 = cb[0];
        int mrow = (lane >> 4) * 4;
#pragma unroll
        for (int i = 0; i < 4; ++i) {
            int pix = pix0 + mrow + i;
            if (pix >= Npix) continue;
            int bi = pix / (NJ * HWD);
            int rem = pix - bi * (NJ * HWD);
            int n = rem / HWD, p = rem - n * HWD;
            outA[((size_t)n * 5 + sel4(cidx, bi)) * HWD + p] = acc[i] + b0;
        }
    }
}

// ---------------- LDS-staged MFMA deformable conv: bf16 LDS, stride 36 shorts ----------------
template <bool INBF, bool OUTF32, bool OUTBF>
__global__ __launch_bounds__(512, 2)
void deform_lds_k(const void* __restrict__ base_, const float* __restrict__ off,
                  const unsigned short* __restrict__ wp, float* __restrict__ outf,
                  unsigned short* __restrict__ outb_, int4 froff) {
    __shared__ unsigned short sf[HWD * 36];  // 78,408 B -> 2 blocks/CU
    int b = blockIdx.x;
    int bi = b / NJ, n = b - bi * NJ;
    if (INBF) {
        const unsigned short* xf = (const unsigned short*)base_ + (size_t)(n + sel4(froff, bi)) * HWD * 32;
        for (int i = threadIdx.x; i < HWD * 4; i += 512) {
            int p = i >> 2, cg = i & 3;  // 8 shorts per copy, 8B-aligned halves
            const unsigned* src = (const unsigned*)(xf + p * 32 + cg * 8);
            unsigned* dst = (unsigned*)(sf + p * 36 + cg * 8);
            dst[0] = src[0]; dst[1] = src[1]; dst[2] = src[2]; dst[3] = src[3];
        }
    } else {
        const float* xf = (const float*)base_ + (size_t)(n + sel4(froff, bi)) * HWD * CC;
        for (int i = threadIdx.x; i < HWD * 4; i += 512) {
            int p = i >> 2, cg = i & 3;
            float4 u0 = *(const float4*)(xf + p * 32 + cg * 8);
            float4 u1 = *(const float4*)(xf + p * 32 + cg * 8 + 4);
            unsigned* dst = (unsigned*)(sf + p * 36 + cg * 8);
            dst[0] = pk2bf(u0.x, u0.y);
            dst[1] = pk2bf(u0.z, u0.w);
            dst[2] = pk2bf(u1.x, u1.y);
            dst[3] = pk2bf(u1.z, u1.w);
        }
    }
    int lane = threadIdx.x & 63;
    int wav  = threadIdx.x >> 6;
    s16x8 bf[18];
#pragma unroll
    for (int i = 0; i < 18; ++i)
        bf[i] = *(const s16x8*)(wp + ((size_t)(i * 64 + lane)) * 8);
    __syncthreads();
    int am = lane & 15, kg = lane >> 4;
    const float* offb = off + (size_t)b * HWD * 18;
    size_t outbase = (size_t)b * HWD * 32;
    for (int tile = wav; tile * 16 < HWD; tile += 8) {
        int pix0 = tile * 16;
        int p = min(pix0 + am, HWD - 1);
        int h = p / WD, q = p - h * WD;
        const float* ofp = offb + (size_t)p * 18;
        float2 dv[9];
#pragma unroll
        for (int kk = 0; kk < 9; ++kk) dv[kk] = *(const float2*)(ofp + 2 * kk);
        f32x4 acc0 = {0.f, 0.f, 0.f, 0.f};
        f32x4 acc1 = {0.f, 0.f, 0.f, 0.f};
#pragma unroll
        for (int kk = 0; kk < 9; ++kk) {
            int ky = kk / 3, kx = kk - ky * 3;
            float py = (float)(h - 1 + ky) + dv[kk].x;
            float px = (float)(q - 1 + kx) + dv[kk].y;
            float y0f = floorf(py), x0f = floorf(px);
            float ly = py - y0f, lx = px - x0f;
            int y0 = (int)y0f, x0 = (int)x0f;
            float w00 = (1.f - ly) * (1.f - lx), w01 = (1.f - ly) * lx;
            float w10 = ly * (1.f - lx), w11 = ly * lx;
            bool yv0 = (y0 >= 0 && y0 < WD), yv1 = (y0 + 1 >= 0 && y0 + 1 < WD);
            bool xv0 = (x0 >= 0 && x0 < WD), xv1 = (x0 + 1 >= 0 && x0 + 1 < WD);
            if (!(yv0 && xv0)) w00 = 0.f;
            if (!(yv0 && xv1)) w01 = 0.f;
            if (!(yv1 && xv0)) w10 = 0.f;
            if (!(yv1 && xv1)) w11 = 0.f;
            int yc0 = min(max(y0, 0), WD - 1), yc1 = min(max(y0 + 1, 0), WD - 1);
            int xc0 = min(max(x0, 0), WD - 1), xc1 = min(max(x0 + 1, 0), WD - 1);
            const unsigned short* s00 = sf + (yc0 * WD + xc0) * 36 + kg * 8;
            const unsigned short* s01 = sf + (yc0 * WD + xc1) * 36 + kg * 8;
            const unsigned short* s10 = sf + (yc1 * WD + xc0) * 36 + kg * 8;
            const unsigned short* s11 = sf + (yc1 * WD + xc1) * 36 + kg * 8;
            s16x8 r00 = *(const s16x8*)(s00);
            s16x8 r01 = *(const s16x8*)(s01);
            s16x8 r10 = *(const s16x8*)(s10);
            s16x8 r11 = *(const s16x8*)(s11);
            float v0 = b2f((unsigned short)r00[0]) * w00 + b2f((unsigned short)r01[0]) * w01
                     + b2f((unsigned short)r10[0]) * w10 + b2f((unsigned short)r11[0]) * w11;
            float v1 = b2f((unsigned short)r00[1]) * w00 + b2f((unsigned short)r01[1]) * w01
                     + b2f((unsigned short)r10[1]) * w10 + b2f((unsigned short)r11[1]) * w11;
            float v2 = b2f((unsigned short)r00[2]) * w00 + b2f((unsigned short)r01[2]) * w01
                     + b2f((unsigned short)r10[2]) * w10 + b2f((unsigned short)r11[2]) * w11;
            float v3 = b2f((unsigned short)r00[3]) * w00 + b2f((unsigned short)r01[3]) * w01
                     + b2f((unsigned short)r10[3]) * w10 + b2f((unsigned short)r11[3]) * w11;
            float v4 = b2f((unsigned short)r00[4]) * w00 + b2f((unsigned short)r01[4]) * w01
                     + b2f((unsigned short)r10[4]) * w10 + b2f((unsigned short)r11[4]) * w11;
            float v5 = b2f((unsigned short)r00[5]) * w00 + b2f((unsigned short)r01[5]) * w01
                     + b2f((unsigned short)r10[5]) * w10 + b2f((unsigned short)r11[5]) * w11;
            float v6 = b2f((unsigned short)r00[6]) * w00 + b2f((unsigned short)r01[6]) * w01
                     + b2f((unsigned short)r10[6]) * w10 + b2f((unsigned short)r11[6]) * w11;
            float v7 = b2f((unsigned short)r00[7]) * w00 + b2f((unsigned short)r01[7]) * w01
                     + b2f((unsigned short)r10[7]) * w10 + b2f((unsigned short)r11[7]) * w11;
            union { s16x8 v; unsigned u[4]; } af;
            af.u[0] = pk2bf(v0, v1);
            af.u[1] = pk2bf(v2, v3);
            af.u[2] = pk2bf(v4, v5);
            af.u[3] = pk2bf(v6, v7);
            acc0 = __builtin_amdgcn_mfma_f32_16x16x32_bf16(af.v, bf[kk * 2 + 0], acc0, 0, 0, 0);
            acc1 = __builtin_amdgcn_mfma_f32_16x16x32_bf16(af.v, bf[kk * 2 + 1], acc1, 0, 0, 0);
        }
        int nn = lane & 15;
        int mrow = (lane >> 4) * 4;
#pragma unroll
        for (int i = 0; i < 4; ++i) {
            int pix = pix0 + mrow + i;
            if (pix >= HWD) continue;
            if (OUTF32) {
                outf[outbase + (size_t)pix * 32 + nn]      = acc0[i];
                outf[outbase + (size_t)pix * 32 + 16 + nn] = acc1[i];
            }
            if (OUTBF) {
                outb_[outbase + (size_t)pix * 32 + nn]      = (unsigned short)f2b(acc0[i]);
                outb_[outbase + (size_t)pix * 32 + 16 + nn] = (unsigned short)f2b(acc1[i]);
            }
        }
    }
}

// ---------------- 3x3 conv NHWC f32 (1 px/thread) — tail ----------------
template <int CIN, int COUT, bool RELU, bool HAS_B, bool HAS_RES>
__global__ __launch_bounds__(256, 2)
void conv3x3_nhwc(const float* __restrict__ in,
                  const float* __restrict__ w, const float* __restrict__ b,
                  const float* __restrict__ res, int res_ps, int res_ns,
                  float* __restrict__ out, int out_ps, int out_ns, int N) {
    constexpr int WROW = (COUT + 3) & ~3;
    __shared__ float wl[9 * CIN * WROW];
    for (int i = threadIdx.x; i < 9 * CIN * WROW; i += 256) {
        int o = i % WROW, r = i / WROW;
        int c = r % CIN, k = r / CIN;
        wl[i] = (o < COUT) ? w[(o * CIN + c) * 9 + k] : 0.f;
    }
    __syncthreads();
    int idx = blockIdx.x * 256 + threadIdx.x;
    if (idx >= N * HWD) return;
    int n = idx / HWD, p = idx % HWD;
    int h = p / WD, q = p % WD;
    float acc[COUT];
#pragma unroll
    for (int o = 0; o < COUT; ++o) acc[o] = HAS_B ? b[o] : 0.f;
    const float* inn = in + (size_t)n * HWD * CIN;
#pragma unroll
    for (int k = 0; k < 9; ++k) {
        int hh = h + k / 3 - 1, qq = q + k % 3 - 1;
        if (hh < 0 || hh >= WD || qq < 0 || qq >= WD) continue;
        const float* ip = inn + (hh * WD + qq) * CIN;
        const float* wk = &wl[k * CIN * WROW];
#pragma unroll
        for (int cg = 0; cg < CIN / 4; ++cg) {
            float4 v = *(const float4*)(ip + cg * 4);
            const float* w0 = wk + (cg * 4) * WROW;
#pragma unroll
            for (int o = 0; o < COUT; ++o)
                acc[o] += v.x * w0[o] + v.y * w0[WROW + o]
                        + v.z * w0[2 * WROW + o] + v.w * w0[3 * WROW + o];
        }
    }
#pragma unroll
    for (int o = 0; o < COUT; ++o) {
        float val = acc[o];
        if (RELU) val = fmaxf(val, 0.f);
        if (HAS_RES) val += res[(size_t)n * res_ns + (size_t)p * res_ps + o];
        out[(size_t)n * out_ns + (size_t)p * out_ps + o] = val;
    }
}

// ---------------- 3x3 conv, CHW input, NHWC f32 out (+optional bf16 copy) ----------------
template <int CIN, int COUT, bool RELU, bool WBF>
__global__ __launch_bounds__(256, 2)
void conv3x3_chwin(const float* __restrict__ in, int in_ns,
                   const float* __restrict__ w, const float* __restrict__ b,
                   float* __restrict__ out, unsigned short* __restrict__ out_bf, int N) {
    __shared__ float wl[CIN * 9 * COUT];
    for (int i = threadIdx.x; i < CIN * 9 * COUT; i += 256) {
        int o = i % COUT, r = i / COUT;
        int k = r % 9, c = r / 9;
        wl[i] = w[(o * CIN + c) * 9 + k];
    }
    __syncthreads();
    int idx = blockIdx.x * 256 + threadIdx.x;
    if (idx >= N * HWD) return;
    int n = idx / HWD, p = idx % HWD;
    int h = p / WD, q = p % WD;
    float acc[COUT];
#pragma unroll
    for (int o = 0; o < COUT; ++o) acc[o] = b[o];
    const float* inn = in + (size_t)n * in_ns;
#pragma unroll
    for (int c = 0; c < CIN; ++c) {
#pragma unroll
        for (int k = 0; k < 9; ++k) {
            int hh = h + k / 3 - 1, qq = q + k % 3 - 1;
            if (hh < 0 || hh >= WD || qq < 0 || qq >= WD) continue;
            float v = inn[c * HWD + hh * WD + qq];
            const float* wp = &wl[(c * 9 + k) * COUT];
#pragma unroll
            for (int o = 0; o < COUT; ++o) acc[o] += v * wp[o];
        }
    }
    float* op = out + ((size_t)idx) * COUT;
#pragma unroll
    for (int o = 0; o < COUT; ++o) {
        float r = RELU ? fmaxf(acc[o], 0.f) : acc[o];
        acc[o] = r;
        op[o] = r;
    }
    if (WBF) {
        unsigned* ob = (unsigned*)(out_bf + (size_t)idx * COUT);
#pragma unroll
        for (int o = 0; o < COUT; o += 2) ob[o >> 1] = pk2bf(acc[o], acc[o + 1]);
    }
}

// ---------------- a1c = 1x1 conv (16 out) of feats[n+2], NHWC ----------------
__global__ void a1c_k(const float* __restrict__ feats, const float* __restrict__ w,
                      const float* __restrict__ b, float* __restrict__ a1c) {
    __shared__ float wl[CC * 16];
    for (int i = threadIdx.x; i < CC * 16; i += 256) {
        int o = i % 16, c = i / 16;
        wl[i] = w[o * CC + c];
    }
    __syncthreads();
    int idx = blockIdx.x * 256 + threadIdx.x;
    if (idx >= NJ * HWD) return;
    int n = idx / HWD, p = idx % HWD;
    const float* f = feats + ((size_t)(n + 2) * HWD + p) * CC;
    float acc[16];
#pragma unroll
    for (int o = 0; o < 16; ++o) acc[o] = b[o];
#pragma unroll
    for (int cg = 0; cg < 8; ++cg) {
        float4 v = *(const float4*)(f + cg * 4);
        const float* w0 = &wl[cg * 4 * 16];
#pragma unroll
        for (int o = 0; o < 16; ++o)
            acc[o] += v.x * w0[o] + v.y * w0[16 + o] + v.z * w0[32 + o] + v.w * w0[48 + o];
    }
    float* op = a1c + (size_t)idx * 16;
#pragma unroll
    for (int o = 0; o < 16; o += 4)
        *(float4*)(op + o) = make_float4(acc[o], acc[o+1], acc[o+2], acc[o+3]);
}

// ---------------- batched: a2 (recomputed) + agg=[mean,max] ----------------
__global__ void aggb_k(const float* __restrict__ feats, const float* __restrict__ w,
                       const float* __restrict__ b, const float* __restrict__ a1c,
                       float* __restrict__ agg, int4 xoff, int N) {
    __shared__ float wl[CC * 16];
    for (int i = threadIdx.x; i < CC * 16; i += 256) {
        int o = i % 16, c = i / 16;
        wl[i] = w[o * CC + c];
    }
    __syncthreads();
    int idx = blockIdx.x * 256 + threadIdx.x;
    if (idx >= N) return;
    int bi = idx / (NJ * HWD);
    int rem = idx - bi * (NJ * HWD);
    int n = rem / HWD, p = rem % HWD;
    int xo = sel4(xoff, bi);
    const float* f = feats + ((size_t)(n + xo) * HWD + p) * CC;
    float acc[16];
#pragma unroll
    for (int o = 0; o < 16; ++o) acc[o] = b[o];
#pragma unroll
    for (int cg = 0; cg < 8; ++cg) {
        float4 v = *(const float4*)(f + cg * 4);
        const float* w0 = &wl[cg * 4 * 16];
#pragma unroll
        for (int o = 0; o < 16; ++o)
            acc[o] += v.x * w0[o] + v.y * w0[16 + o] + v.z * w0[32 + o] + v.w * w0[48 + o];
    }
    float sum = 0.f, mx = -1e30f;
    const float* ap = a1c + (size_t)rem * 16;
#pragma unroll
    for (int o = 0; o < 16; ++o) {
        float v = ap[o];
        sum += v; mx = fmaxf(mx, v);
    }
#pragma unroll
    for (int o = 0; o < 16; ++o) {
        sum += acc[o]; mx = fmaxf(mx, acc[o]);
    }
    agg[(size_t)idx * 2 + 0] = sum * (1.f / 32.f);
    agg[(size_t)idx * 2 + 1] = mx;
}

// ---------------- batched: sig; fused(bf16) = [a1c*g0, a2*g1] ----------------
__global__ void sigfusedb_k(const float* __restrict__ agg, const float* __restrict__ sqw,
                            const float* __restrict__ sqb, const float* __restrict__ a1c,
                            const float* __restrict__ feats, const float* __restrict__ w,
                            const float* __restrict__ b, unsigned short* __restrict__ fused,
                            int4 xoff, int N) {
    __shared__ float wl[CC * 16];
    for (int i = threadIdx.x; i < CC * 16; i += 256) {
        int o = i % 16, c = i / 16;
        wl[i] = w[o * CC + c];
    }
    __syncthreads();
    int idx = blockIdx.x * 256 + threadIdx.x;
    if (idx >= N) return;
    int bi = idx / (NJ * HWD);
    int rem = idx - bi * (NJ * HWD);
    int n = rem / HWD, p = rem % HWD;
    int h = p / WD, q = p % WD;
    float s0 = sqb[0], s1 = sqb[1];
    const float* ag = agg + (size_t)(idx - p) * 2;
#pragma unroll
    for (int k = 0; k < 9; ++k) {
        int hh = h + k / 3 - 1, qq = q + k % 3 - 1;
        if (hh < 0 || hh >= WD || qq < 0 || qq >= WD) continue;
        float2 v = *(const float2*)(ag + (hh * WD + qq) * 2);
        s0 += v.x * sqw[0 * 18 + 0 * 9 + k] + v.y * sqw[0 * 18 + 1 * 9 + k];
        s1 += v.x * sqw[1 * 18 + 0 * 9 + k] + v.y * sqw[1 * 18 + 1 * 9 + k];
    }
    float g0 = sigm(s0), g1 = sigm(s1);
    int xo = sel4(xoff, bi);
    const float* f = feats + ((size_t)(n + xo) * HWD + p) * CC;
    float acc[16];
#pragma unroll
    for (int o = 0; o < 16; ++o) acc[o] = b[o];
#pragma unroll
    for (int cg = 0; cg < 8; ++cg) {
        float4 v = *(const float4*)(f + cg * 4);
        const float* w0 = &wl[cg * 4 * 16];
#pragma unroll
        for (int o = 0; o < 16; ++o)
            acc[o] += v.x * w0[o] + v.y * w0[16 + o] + v.z * w0[32 + o] + v.w * w0[48 + o];
    }
    const float* ap = a1c + (size_t)rem * 16;
    unsigned* fp = (unsigned*)(fused + (size_t)idx * CC);
#pragma unroll
    for (int o = 0; o < 16; o += 2)
        fp[o >> 1] = pk2bf(ap[o] * g0, ap[o + 1] * g0);
#pragma unroll
    for (int o = 0; o < 16; o += 2)
        fp[8 + (o >> 1)] = pk2bf(acc[o] * g1, acc[o + 1] * g1);
}

// ---------------- cen_raw into aligned ch2 + arange output ----------------
__global__ void misc_k(const float* __restrict__ imgs, float* __restrict__ out) {
    int idx = blockIdx.x * 256 + threadIdx.x;
    float* alig = out + 135036 + 124;
    if (idx < NJ * HWD) {
        int n = idx / HWD, p = idx % HWD;
        alig[((size_t)n * 5 + 2) * HWD + p] = imgs[(size_t)(n + 2) * HWD + p];
    }
    if (idx < NJ) out[135036 + idx] = (float)(idx + 2);
}

extern "C" void kernel_launch(void* const* d_in, const int* in_sizes, int n_in,
                              void* d_out, int out_size, void* d_ws, size_t ws_size,
                              hipStream_t stream) {
    const float* x      = (const float*)d_in[0];
    const float* mlp_w  = (const float*)d_in[1];
    const float* mlp_b  = (const float*)d_in[2];
    const float* fe_w   = (const float*)d_in[3];
    const float* fe_b   = (const float*)d_in[4];
    const float* c0_w   = (const float*)d_in[5];
    const float* c0_b   = (const float*)d_in[6];
    const float* c1_w   = (const float*)d_in[7];
    const float* c1_b   = (const float*)d_in[8];
    const float* sq_w   = (const float*)d_in[9];
    const float* sq_b   = (const float*)d_in[10];
    const float* off1_w = (const float*)d_in[11];
    const float* off1_b = (const float*)d_in[12];
    const float* dw1    = (const float*)d_in[13];
    const float* off2_w = (const float*)d_in[14];
    const float* off2_b = (const float*)d_in[15];
    const float* dw2    = (const float*)d_in[16];
    const float* conv_w = (const float*)d_in[17];
    const float* conv_b = (const float*)d_in[18];
    const float* tc0_w  = (const float*)d_in[19];
    const float* tc0_b  = (const float*)d_in[20];
    const float* rb_w1  = (const float*)d_in[21];
    const float* rb_b1  = (const float*)d_in[22];
    const float* rb_w2  = (const float*)d_in[23];
    const float* rb_b2  = (const float*)d_in[24];
    const float* tail_w = (const float*)d_in[25];

    const size_t FRAME = (size_t)NJ * HWD;  // 135036

    const size_t baseB = ((size_t)1089 + NF * HWD + (size_t)NF * HWD * 32 + FRAME * 16) * 4 + 1024;
    const size_t perBB = FRAME * (2 * 4 + 32 * 2 + 18 * 4 + 32 * 2) + 512;
    int nb = 4;
    while (nb > 1 && baseB + (size_t)nb * perBB > ws_size) nb >>= 1;

    char* cur = (char*)d_ws;
    auto alloc = [&](size_t bytes) { char* p = cur; cur += (bytes + 63) & ~(size_t)63; return p; };
    float* rs    = (float*)alloc(1089 * 4);
    float* imgs  = (float*)alloc((size_t)NF * HWD * 4);
    float* feats = (float*)alloc((size_t)NF * HWD * 32 * 4);
    float* a1c   = (float*)alloc(FRAME * 16 * 4);
    float* agg   = (float*)alloc((size_t)nb * FRAME * 2 * 4);
    unsigned short* fused_bf = (unsigned short*)alloc((size_t)nb * FRAME * 32 * 2);
    float* offb  = (float*)alloc((size_t)nb * FRAME * 18 * 4);
    unsigned short* al1_bf = (unsigned short*)alloc((size_t)nb * FRAME * 32 * 2);

    float* hbuf = feats;
    unsigned short* hbuf_bf = (unsigned short*)a1c;
    unsigned short* tmp_bf  = fused_bf;
    unsigned short* al2_bf  = fused_bf;
    unsigned short* wpack = (unsigned short*)imgs;
    unsigned short* wp_off1 = wpack + 0 * 9216;
    unsigned short* wp_off2 = wpack + 1 * 9216;
    unsigned short* wp_dw1  = wpack + 12 * 9216;
    unsigned short* wp_dw2  = wpack + 13 * 9216;
    unsigned short* wp_cw   = wpack + 14 * 9216;

    float* outF = (float*)d_out;
    float* outA = outF + 135036 + 124;

    const int GF = (NF * HWD + 255) / 256;
    const int GJ = (NJ * HWD + 255) / 256;

    rowsum_k<<<HWD, 256, 0, stream>>>(mlp_w, rs);
    imgs_k<<<GF, 256, 0, stream>>>(x, rs, mlp_b, imgs);
    conv3x3_chwin<1, 32, true, false><<<GF, 256, 0, stream>>>(imgs, HWD, fe_w, fe_b, feats, nullptr, NF);
    misc_k<<<GJ, 256, 0, stream>>>(imgs, outF);
    pack_k<<<(15 * 9216 + 255) / 256, 256, 0, stream>>>(off1_w, off2_w, rb_w1, rb_w2, dw1, dw2, conv_w, wpack);
    a1c_k<<<GJ, 256, 0, stream>>>(feats, c0_w, c0_b, a1c);

    const int xoffs_all[4] = {0, 1, 3, 4};
    const int cidx_all[4]  = {0, 1, 3, 4};
    for (int pb = 0; pb < 4; pb += nb) {
        int4 xo = make_int4(xoffs_all[pb],
                            xoffs_all[(pb + 1) & 3],
                            xoffs_all[(pb + 2) & 3],
                            xoffs_all[(pb + 3) & 3]);
        int4 ci = make_int4(cidx_all[pb],
                            cidx_all[(pb + 1) & 3],
                            cidx_all[(pb + 2) & 3],
                            cidx_all[(pb + 3) & 3]);
        int4 f2 = make_int4(0, NJ, 2 * NJ, 3 * NJ);
        int N = nb * (int)FRAME;
        int GB = (N + 255) / 256;
        int GM = (N + 63) / 64;
        aggb_k<<<GB, 256, 0, stream>>>(feats, c1_w, c1_b, a1c, agg, xo, N);
        sigfusedb_k<<<GB, 256, 0, stream>>>(agg, sq_w, sq_b, a1c, feats, c1_w, c1_b, fused_bf, xo, N);
        mfmaconv_k<18, false, false, true, false><<<GM, 256, 0, stream>>>(
            fused_bf, wp_off1, off1_b, nullptr, offb, 18, nullptr, N);
        deform_lds_k<false, false, true><<<nb * NJ, 512, 0, stream>>>(
            feats, offb, wp_dw1, nullptr, al1_bf, xo);
        mfmaconv_k<18, false, false, true, false><<<GM, 256, 0, stream>>>(
            al1_bf, wp_off2, off2_b, nullptr, offb, 18, nullptr, N);
        deform_lds_k<true, false, true><<<nb * NJ, 512, 0, stream>>>(
            al1_bf, offb, wp_dw2, nullptr, al2_bf, f2);
        convout_mfma_k<<<GM, 256, 0, stream>>>(al2_bf, wp_cw, conv_b, outA, ci, N);
    }

    conv3x3_chwin<5, 32, true, true><<<GJ, 256, 0, stream>>>(
        outA, 5 * HWD, tc0_w, tc0_b, hbuf, hbuf_bf, NJ);
    const int GMF = ((int)FRAME + 63) / 64;
    for (int l = 0; l < 5; ++l) {
        mfmaconv_k<32, true, false, false, true><<<GMF, 256, 0, stream>>>(
            hbuf_bf, wpack + (size_t)(2 + l) * 9216, rb_b1 + l * CC, nullptr,
            nullptr, 0, tmp_bf, (int)FRAME);
        mfmaconv_k<32, false, true, true, true><<<GMF, 256, 0, stream>>>(
            tmp_bf, wpack + (size_t)(7 + l) * 9216, rb_b2 + l * CC, hbuf,
            hbuf, 32, hbuf_bf, (int)FRAME);
    }
    conv3x3_nhwc<32, 1, false, false, false><<<GJ, 256, 0, stream>>>(
        hbuf, tail_w, nullptr, nullptr, 0, 0, outF, 1, HWD, NJ);
}

// Round 17
// 609.118 us; speedup vs baseline: 1.2746x; 1.2746x over previous
//
#include <hip/hip_runtime.h>
#include <math.h>

#define HWD 1089
#define WD 33
#define NF 128
#define NJ 124
#define CC 32

typedef __attribute__((ext_vector_type(8))) short s16x8;
typedef __attribute__((ext_vector_type(4))) float f32x4;

__device__ __forceinline__ float sigm(float z) { return 1.f / (1.f + expf(-z)); }
__device__ __forceinline__ int sel4(int4 v, int i) { return i == 0 ? v.x : i == 1 ? v.y : i == 2 ? v.z : v.w; }
__device__ __forceinline__ short f2b(float f) {
    union { float f; unsigned u; } x; x.f = f;
    unsigned r = x.u + 0x7fffu + ((x.u >> 16) & 1u);
    return (short)(r >> 16);
}
__device__ __forceinline__ float b2f(unsigned short u) {
    union { unsigned u; float f; } x; x.u = (unsigned)u << 16;
    return x.f;
}
__device__ __forceinline__ unsigned pk2bf(float a, float b) {
    unsigned r;
    asm("v_cvt_pk_bf16_f32 %0, %1, %2" : "=v"(r) : "v"(a), "v"(b));
    return r;
}

// ---------------- rs[j] = sum_k mlp_w[j][k] ----------------
__global__ void rowsum_k(const float* __restrict__ mw, float* __restrict__ rs) {
    int j = blockIdx.x;
    const float* row = mw + (size_t)j * HWD;
    float s = 0.f;
    for (int k = threadIdx.x; k < HWD; k += 256) s += row[k];
    __shared__ float red[256];
    red[threadIdx.x] = s; __syncthreads();
    for (int off = 128; off > 0; off >>= 1) {
        if (threadIdx.x < off) red[threadIdx.x] += red[threadIdx.x + off];
        __syncthreads();
    }
    if (threadIdx.x == 0) rs[j] = red[0];
}

// ---------------- imgs = x * sigmoid((t/20)*rs + mlp_b) ----------------
__global__ void imgs_k(const float* __restrict__ x, const float* __restrict__ rs,
                       const float* __restrict__ mb, float* __restrict__ imgs) {
    int idx = blockIdx.x * 256 + threadIdx.x;
    if (idx >= NF * HWD) return;
    int t = idx / HWD, p = idx % HWD;
    float pe = sigm(((float)t / 20.0f) * rs[p] + mb[p]);
    imgs[idx] = x[idx] * pe;
}

// ---------------- weight pack: 15 tensors -> bf16 MFMA B-fragments ----------------
// t: 0=off1_w(18) 1=off2_w(18) 2..6=rb_w1[l](32) 7..11=rb_w2[l](32) 12=dw1(32) 13=dw2(32) 14=conv_w(1)
__global__ void pack_k(const float* __restrict__ off1_w, const float* __restrict__ off2_w,
                       const float* __restrict__ rb_w1, const float* __restrict__ rb_w2,
                       const float* __restrict__ dw1, const float* __restrict__ dw2,
                       const float* __restrict__ conv_w, unsigned short* __restrict__ wp) {
    int tid = blockIdx.x * 256 + threadIdx.x;
    if (tid >= 15 * 9216) return;
    int t = tid / 9216, u = tid - t * 9216;
    int j = u & 7, l = (u >> 3) & 63, h = (u >> 9) & 1, k = u >> 10;
    int o = h * 16 + (l & 15);
    int c = 8 * (l >> 4) + j;
    const float* src;
    int cout;
    if (t == 0)       { src = off1_w; cout = 18; }
    else if (t == 1)  { src = off2_w; cout = 18; }
    else if (t < 7)   { src = rb_w1 + (size_t)(t - 2) * 9216; cout = 32; }
    else if (t < 12)  { src = rb_w2 + (size_t)(t - 7) * 9216; cout = 32; }
    else if (t == 12) { src = dw1; cout = 32; }
    else if (t == 13) { src = dw2; cout = 32; }
    else              { src = conv_w; cout = 1; }
    float val = (o < cout) ? src[(o * 32 + c) * 9 + k] : 0.f;
    wp[tid] = (unsigned short)f2b(val);
}

// ---------------- MFMA 3x3 conv, bf16 NHWC input, COUT out, 9-tap prefetch ----------------
template <int COUT, bool RELU, bool HAS_RES, bool WF32, bool WBF>
__global__ __launch_bounds__(256, 2)
void mfmaconv_k(const unsigned short* __restrict__ in, const unsigned short* __restrict__ wp,
                const float* __restrict__ bias, const float* __restrict__ res,
                float* __restrict__ outf, int out_ps, unsigned short* __restrict__ outb_,
                int Npix) {
    int lane = threadIdx.x & 63;
    int wav  = threadIdx.x >> 6;
    int pix0 = (blockIdx.x * 4 + wav) * 16;
    if (pix0 >= Npix) return;
    s16x8 bf[18];
#pragma unroll
    for (int i = 0; i < 18; ++i)
        bf[i] = *(const s16x8*)(wp + ((size_t)(i * 64 + lane)) * 8);
    int am = lane & 15;
    int ak = lane >> 4;
    int apix = pix0 + am;
    bool aval = apix < Npix;
    int apixc = min(apix, Npix - 1);
    int ap = apixc % HWD;
    int ah = ap / WD, aq = ap - ah * WD;
    const unsigned short* abase = in + (size_t)apixc * 32 + ak * 8;
    s16x8 u[9];
    bool vm[9];
#pragma unroll
    for (int k = 0; k < 9; ++k) {
        int dy = k / 3 - 1, dx = k % 3 - 1;
        int hh = ah + dy, qq = aq + dx;
        vm[k] = aval && hh >= 0 && hh < WD && qq >= 0 && qq < WD;
        const unsigned short* ipp = vm[k] ? (abase + (dy * WD + dx) * 32) : abase;
        u[k] = *(const s16x8*)(ipp);
    }
    const s16x8 zz = {0, 0, 0, 0, 0, 0, 0, 0};
    f32x4 acc0 = {0.f, 0.f, 0.f, 0.f};
    f32x4 acc1 = {0.f, 0.f, 0.f, 0.f};
#pragma unroll
    for (int k = 0; k < 9; ++k) {
        s16x8 af = vm[k] ? u[k] : zz;
        acc0 = __builtin_amdgcn_mfma_f32_16x16x32_bf16(af, bf[k * 2 + 0], acc0, 0, 0, 0);
        acc1 = __builtin_amdgcn_mfma_f32_16x16x32_bf16(af, bf[k * 2 + 1], acc1, 0, 0, 0);
    }
    int n = lane & 15;
    int mrow = (lane >> 4) * 4;
    float b0 = bias[n];
    float b1 = (16 + n < COUT) ? bias[16 + n] : 0.f;
#pragma unroll
    for (int i = 0; i < 4; ++i) {
        int pix = pix0 + mrow + i;
        if (pix >= Npix) continue;
        float v0 = acc0[i] + b0;
        if (RELU) v0 = fmaxf(v0, 0.f);
        if (HAS_RES) v0 += res[(size_t)pix * 32 + n];
        if (WF32) outf[(size_t)pix * out_ps + n] = v0;
        if (WBF) outb_[(size_t)pix * 32 + n] = (unsigned short)f2b(v0);
        if (16 + n < COUT) {
            float v1 = acc1[i] + b1;
            if (RELU) v1 = fmaxf(v1, 0.f);
            if (HAS_RES) v1 += res[(size_t)pix * 32 + 16 + n];
            if (WF32) outf[(size_t)pix * out_ps + 16 + n] = v1;
            if (WBF) outb_[(size_t)pix * 32 + 16 + n] = (unsigned short)f2b(v1);
        }
    }
}

// ---------------- MFMA 3x3 conv 32->1 (bf16 in) -> aligned NCHW channel ----------------
__global__ __launch_bounds__(256, 2)
void convout_mfma_k(const unsigned short* __restrict__ in, const unsigned short* __restrict__ wp,
                    const float* __restrict__ cb, float* __restrict__ outA, int4 cidx, int Npix) {
    int lane = threadIdx.x & 63;
    int wav  = threadIdx.x >> 6;
    int pix0 = (blockIdx.x * 4 + wav) * 16;
    if (pix0 >= Npix) return;
    s16x8 bc[9];
#pragma unroll
    for (int k = 0; k < 9; ++k)
        bc[k] = *(const s16x8*)(wp + ((size_t)((k * 2 + 0) * 64 + lane)) * 8);
    int am = lane & 15, ak = lane >> 4;
    int apix = pix0 + am;
    bool aval = apix < Npix;
    int apixc = min(apix, Npix - 1);
    int ap = apixc % HWD;
    int ah = ap / WD, aq = ap - ah * WD;
    const unsigned short* abase = in + (size_t)apixc * 32 + ak * 8;
    s16x8 u[9];
    bool vm[9];
#pragma unroll
    for (int k = 0; k < 9; ++k) {
        int dy = k / 3 - 1, dx = k % 3 - 1;
        int hh = ah + dy, qq = aq + dx;
        vm[k] = aval && hh >= 0 && hh < WD && qq >= 0 && qq < WD;
        const unsigned short* ipp = vm[k] ? (abase + (dy * WD + dx) * 32) : abase;
        u[k] = *(const s16x8*)(ipp);
    }
    const s16x8 zz = {0, 0, 0, 0, 0, 0, 0, 0};
    f32x4 acc = {0.f, 0.f, 0.f, 0.f};
#pragma unroll
    for (int k = 0; k < 9; ++k)
        acc = __builtin_amdgcn_mfma_f32_16x16x32_bf16(vm[k] ? u[k] : zz, bc[k], acc, 0, 0, 0);
    if ((lane & 15) == 0) {
        float b0 = cb[0];
        int mrow = (lane >> 4) * 4;
#pragma unroll
        for (int i = 0; i < 4; ++i) {
            int pix = pix0 + mrow + i;
            if (pix >= Npix) continue;
            int bi = pix / (NJ * HWD);
            int rem = pix - bi * (NJ * HWD);
            int n = rem / HWD, p = rem - n * HWD;
            outA[((size_t)n * 5 + sel4(cidx, bi)) * HWD + p] = acc[i] + b0;
        }
    }
}

// ---------------- LDS-staged MFMA deformable conv: f32 LDS stride 36 floats, 16 waves ----------------
template <bool INBF, bool OUTF32, bool OUTBF>
__global__ __launch_bounds__(1024, 1)
void deform_lds_k(const void* __restrict__ base_, const float* __restrict__ off,
                  const unsigned short* __restrict__ wp, float* __restrict__ outf,
                  unsigned short* __restrict__ outb_, int4 froff) {
    __shared__ float sf[HWD * 36];  // 156,816 B
    int b = blockIdx.x;
    int bi = b / NJ, n = b - bi * NJ;
    if (INBF) {
        const unsigned short* xf = (const unsigned short*)base_ + (size_t)(n + sel4(froff, bi)) * HWD * 32;
        for (int i = threadIdx.x; i < HWD * 4; i += 1024) {
            int p = i >> 2, cg = i & 3;
            s16x8 v = *(const s16x8*)(xf + p * 32 + cg * 8);
            float4 f0 = make_float4(b2f((unsigned short)v[0]), b2f((unsigned short)v[1]),
                                    b2f((unsigned short)v[2]), b2f((unsigned short)v[3]));
            float4 f1 = make_float4(b2f((unsigned short)v[4]), b2f((unsigned short)v[5]),
                                    b2f((unsigned short)v[6]), b2f((unsigned short)v[7]));
            *(float4*)(sf + p * 36 + cg * 8) = f0;
            *(float4*)(sf + p * 36 + cg * 8 + 4) = f1;
        }
    } else {
        const float* xf = (const float*)base_ + (size_t)(n + sel4(froff, bi)) * HWD * CC;
        for (int i = threadIdx.x; i < HWD * 8; i += 1024) {
            int p = i >> 3, cg = i & 7;
            *(float4*)(sf + p * 36 + cg * 4) = *(const float4*)(xf + p * 32 + cg * 4);
        }
    }
    int lane = threadIdx.x & 63;
    int wav  = threadIdx.x >> 6;
    s16x8 bf[18];
#pragma unroll
    for (int i = 0; i < 18; ++i)
        bf[i] = *(const s16x8*)(wp + ((size_t)(i * 64 + lane)) * 8);
    __syncthreads();
    int am = lane & 15, kg = lane >> 4;
    const float* offb = off + (size_t)b * HWD * 18;
    size_t outbase = (size_t)b * HWD * 32;
    for (int tile = wav; tile * 16 < HWD; tile += 16) {
        int pix0 = tile * 16;
        int p = min(pix0 + am, HWD - 1);
        int h = p / WD, q = p - h * WD;
        const float* ofp = offb + (size_t)p * 18;
        float2 dv[9];
#pragma unroll
        for (int kk = 0; kk < 9; ++kk) dv[kk] = *(const float2*)(ofp + 2 * kk);
        f32x4 acc0 = {0.f, 0.f, 0.f, 0.f};
        f32x4 acc1 = {0.f, 0.f, 0.f, 0.f};
#pragma unroll
        for (int kk = 0; kk < 9; ++kk) {
            int ky = kk / 3, kx = kk - ky * 3;
            float py = (float)(h - 1 + ky) + dv[kk].x;
            float px = (float)(q - 1 + kx) + dv[kk].y;
            float y0f = floorf(py), x0f = floorf(px);
            float ly = py - y0f, lx = px - x0f;
            int y0 = (int)y0f, x0 = (int)x0f;
            float w00 = (1.f - ly) * (1.f - lx), w01 = (1.f - ly) * lx;
            float w10 = ly * (1.f - lx), w11 = ly * lx;
            bool yv0 = (y0 >= 0 && y0 < WD), yv1 = (y0 + 1 >= 0 && y0 + 1 < WD);
            bool xv0 = (x0 >= 0 && x0 < WD), xv1 = (x0 + 1 >= 0 && x0 + 1 < WD);
            if (!(yv0 && xv0)) w00 = 0.f;
            if (!(yv0 && xv1)) w01 = 0.f;
            if (!(yv1 && xv0)) w10 = 0.f;
            if (!(yv1 && xv1)) w11 = 0.f;
            int yc0 = min(max(y0, 0), WD - 1), yc1 = min(max(y0 + 1, 0), WD - 1);
            int xc0 = min(max(x0, 0), WD - 1), xc1 = min(max(x0 + 1, 0), WD - 1);
            const float* s00 = sf + (yc0 * WD + xc0) * 36 + kg * 8;
            const float* s01 = sf + (yc0 * WD + xc1) * 36 + kg * 8;
            const float* s10 = sf + (yc1 * WD + xc0) * 36 + kg * 8;
            const float* s11 = sf + (yc1 * WD + xc1) * 36 + kg * 8;
            float4 a0 = *(const float4*)(s00);
            float4 a1 = *(const float4*)(s00 + 4);
            float4 b0 = *(const float4*)(s01);
            float4 b1 = *(const float4*)(s01 + 4);
            float4 c0 = *(const float4*)(s10);
            float4 c1 = *(const float4*)(s10 + 4);
            float4 d0 = *(const float4*)(s11);
            float4 d1 = *(const float4*)(s11 + 4);
            float v0 = a0.x * w00 + b0.x * w01 + c0.x * w10 + d0.x * w11;
            float v1 = a0.y * w00 + b0.y * w01 + c0.y * w10 + d0.y * w11;
            float v2 = a0.z * w00 + b0.z * w01 + c0.z * w10 + d0.z * w11;
            float v3 = a0.w * w00 + b0.w * w01 + c0.w * w10 + d0.w * w11;
            float v4 = a1.x * w00 + b1.x * w01 + c1.x * w10 + d1.x * w11;
            float v5 = a1.y * w00 + b1.y * w01 + c1.y * w10 + d1.y * w11;
            float v6 = a1.z * w00 + b1.z * w01 + c1.z * w10 + d1.z * w11;
            float v7 = a1.w * w00 + b1.w * w01 + c1.w * w10 + d1.w * w11;
            union { s16x8 v; unsigned u[4]; } af;
            af.u[0] = pk2bf(v0, v1);
            af.u[1] = pk2bf(v2, v3);
            af.u[2] = pk2bf(v4, v5);
            af.u[3] = pk2bf(v6, v7);
            acc0 = __builtin_amdgcn_mfma_f32_16x16x32_bf16(af.v, bf[kk * 2 + 0], acc0, 0, 0, 0);
            acc1 = __builtin_amdgcn_mfma_f32_16x16x32_bf16(af.v, bf[kk * 2 + 1], acc1, 0, 0, 0);
        }
        int nn = lane & 15;
        int mrow = (lane >> 4) * 4;
#pragma unroll
        for (int i = 0; i < 4; ++i) {
            int pix = pix0 + mrow + i;
            if (pix >= HWD) continue;
            if (OUTF32) {
                outf[outbase + (size_t)pix * 32 + nn]      = acc0[i];
                outf[outbase + (size_t)pix * 32 + 16 + nn] = acc1[i];
            }
            if (OUTBF) {
                outb_[outbase + (size_t)pix * 32 + nn]      = (unsigned short)f2b(acc0[i]);
                outb_[outbase + (size_t)pix * 32 + 16 + nn] = (unsigned short)f2b(acc1[i]);
            }
        }
    }
}

// ---------------- 3x3 conv NHWC f32 (1 px/thread) — tail ----------------
template <int CIN, int COUT, bool RELU, bool HAS_B, bool HAS_RES>
__global__ __launch_bounds__(256, 2)
void conv3x3_nhwc(const float* __restrict__ in,
                  const float* __restrict__ w, const float* __restrict__ b,
                  const float* __restrict__ res, int res_ps, int res_ns,
                  float* __restrict__ out, int out_ps, int out_ns, int N) {
    constexpr int WROW = (COUT + 3) & ~3;
    __shared__ float wl[9 * CIN * WROW];
    for (int i = threadIdx.x; i < 9 * CIN * WROW; i += 256) {
        int o = i % WROW, r = i / WROW;
        int c = r % CIN, k = r / CIN;
        wl[i] = (o < COUT) ? w[(o * CIN + c) * 9 + k] : 0.f;
    }
    __syncthreads();
    int idx = blockIdx.x * 256 + threadIdx.x;
    if (idx >= N * HWD) return;
    int n = idx / HWD, p = idx % HWD;
    int h = p / WD, q = p % WD;
    float acc[COUT];
#pragma unroll
    for (int o = 0; o < COUT; ++o) acc[o] = HAS_B ? b[o] : 0.f;
    const float* inn = in + (size_t)n * HWD * CIN;
#pragma unroll
    for (int k = 0; k < 9; ++k) {
        int hh = h + k / 3 - 1, qq = q + k % 3 - 1;
        if (hh < 0 || hh >= WD || qq < 0 || qq >= WD) continue;
        const float* ip = inn + (hh * WD + qq) * CIN;
        const float* wk = &wl[k * CIN * WROW];
#pragma unroll
        for (int cg = 0; cg < CIN / 4; ++cg) {
            float4 v = *(const float4*)(ip + cg * 4);
            const float* w0 = wk + (cg * 4) * WROW;
#pragma unroll
            for (int o = 0; o < COUT; ++o)
                acc[o] += v.x * w0[o] + v.y * w0[WROW + o]
                        + v.z * w0[2 * WROW + o] + v.w * w0[3 * WROW + o];
        }
    }
#pragma unroll
    for (int o = 0; o < COUT; ++o) {
        float val = acc[o];
        if (RELU) val = fmaxf(val, 0.f);
        if (HAS_RES) val += res[(size_t)n * res_ns + (size_t)p * res_ps + o];
        out[(size_t)n * out_ns + (size_t)p * out_ps + o] = val;
    }
}

// ---------------- 3x3 conv, CHW input, NHWC f32 out (+optional bf16 copy) ----------------
template <int CIN, int COUT, bool RELU, bool WBF>
__global__ __launch_bounds__(256, 2)
void conv3x3_chwin(const float* __restrict__ in, int in_ns,
                   const float* __restrict__ w, const float* __restrict__ b,
                   float* __restrict__ out, unsigned short* __restrict__ out_bf, int N) {
    __shared__ float wl[CIN * 9 * COUT];
    for (int i = threadIdx.x; i < CIN * 9 * COUT; i += 256) {
        int o = i % COUT, r = i / COUT;
        int k = r % 9, c = r / 9;
        wl[i] = w[(o * CIN + c) * 9 + k];
    }
    __syncthreads();
    int idx = blockIdx.x * 256 + threadIdx.x;
    if (idx >= N * HWD) return;
    int n = idx / HWD, p = idx % HWD;
    int h = p / WD, q = p % WD;
    float acc[COUT];
#pragma unroll
    for (int o = 0; o < COUT; ++o) acc[o] = b[o];
    const float* inn = in + (size_t)n * in_ns;
#pragma unroll
    for (int c = 0; c < CIN; ++c) {
#pragma unroll
        for (int k = 0; k < 9; ++k) {
            int hh = h + k / 3 - 1, qq = q + k % 3 - 1;
            if (hh < 0 || hh >= WD || qq < 0 || qq >= WD) continue;
            float v = inn[c * HWD + hh * WD + qq];
            const float* wp = &wl[(c * 9 + k) * COUT];
#pragma unroll
            for (int o = 0; o < COUT; ++o) acc[o] += v * wp[o];
        }
    }
    float* op = out + ((size_t)idx) * COUT;
#pragma unroll
    for (int o = 0; o < COUT; ++o) {
        float r = RELU ? fmaxf(acc[o], 0.f) : acc[o];
        acc[o] = r;
        op[o] = r;
    }
    if (WBF) {
        unsigned* ob = (unsigned*)(out_bf + (size_t)idx * COUT);
#pragma unroll
        for (int o = 0; o < COUT; o += 2) ob[o >> 1] = pk2bf(acc[o], acc[o + 1]);
    }
}

// ---------------- a1c = 1x1 conv (16 out) of feats[n+2], NHWC ----------------
__global__ void a1c_k(const float* __restrict__ feats, const float* __restrict__ w,
                      const float* __restrict__ b, float* __restrict__ a1c) {
    __shared__ float wl[CC * 16];
    for (int i = threadIdx.x; i < CC * 16; i += 256) {
        int o = i % 16, c = i / 16;
        wl[i] = w[o * CC + c];
    }
    __syncthreads();
    int idx = blockIdx.x * 256 + threadIdx.x;
    if (idx >= NJ * HWD) return;
    int n = idx / HWD, p = idx % HWD;
    const float* f = feats + ((size_t)(n + 2) * HWD + p) * CC;
    float acc[16];
#pragma unroll
    for (int o = 0; o < 16; ++o) acc[o] = b[o];
#pragma unroll
    for (int cg = 0; cg < 8; ++cg) {
        float4 v = *(const float4*)(f + cg * 4);
        const float* w0 = &wl[cg * 4 * 16];
#pragma unroll
        for (int o = 0; o < 16; ++o)
            acc[o] += v.x * w0[o] + v.y * w0[16 + o] + v.z * w0[32 + o] + v.w * w0[48 + o];
    }
    float* op = a1c + (size_t)idx * 16;
#pragma unroll
    for (int o = 0; o < 16; o += 4)
        *(float4*)(op + o) = make_float4(acc[o], acc[o+1], acc[o+2], acc[o+3]);
}

// ---------------- batched: a2 (recomputed) + agg=[mean,max] ----------------
__global__ void aggb_k(const float* __restrict__ feats, const float* __restrict__ w,
                       const float* __restrict__ b, const float* __restrict__ a1c,
                       float* __restrict__ agg, int4 xoff, int N) {
    __shared__ float wl[CC * 16];
    for (int i = threadIdx.x; i < CC * 16; i += 256) {
        int o = i % 16, c = i / 16;
        wl[i] = w[o * CC + c];
    }
    __syncthreads();
    int idx = blockIdx.x * 256 + threadIdx.x;
    if (idx >= N) return;
    int bi = idx / (NJ * HWD);
    int rem = idx - bi * (NJ * HWD);
    int n = rem / HWD, p = rem % HWD;
    int xo = sel4(xoff, bi);
    const float* f = feats + ((size_t)(n + xo) * HWD + p) * CC;
    float acc[16];
#pragma unroll
    for (int o = 0; o < 16; ++o) acc[o] = b[o];
#pragma unroll
    for (int cg = 0; cg < 8; ++cg) {
        float4 v = *(const float4*)(f + cg * 4);
        const float* w0 = &wl[cg * 4 * 16];
#pragma unroll
        for (int o = 0; o < 16; ++o)
            acc[o] += v.x * w0[o] + v.y * w0[16 + o] + v.z * w0[32 + o] + v.w * w0[48 + o];
    }
    float sum = 0.f, mx = -1e30f;
    const float* ap = a1c + (size_t)rem * 16;
#pragma unroll
    for (int o = 0; o < 16; ++o) {
        float v = ap[o];
        sum += v; mx = fmaxf(mx, v);
    }
#pragma unroll
    for (int o = 0; o < 16; ++o) {
        sum += acc[o]; mx = fmaxf(mx, acc[o]);
    }
    agg[(size_t)idx * 2 + 0] = sum * (1.f / 32.f);
    agg[(size_t)idx * 2 + 1] = mx;
}

// ---------------- batched: sig; fused(bf16) = [a1c*g0, a2*g1] ----------------
__global__ void sigfusedb_k(const float* __restrict__ agg, const float* __restrict__ sqw,
                            const float* __restrict__ sqb, const float* __restrict__ a1c,
                            const float* __restrict__ feats, const float* __restrict__ w,
                            const float* __restrict__ b, unsigned short* __restrict__ fused,
                            int4 xoff, int N) {
    __shared__ float wl[CC * 16];
    for (int i = threadIdx.x; i < CC * 16; i += 256) {
        int o = i % 16, c = i / 16;
        wl[i] = w[o * CC + c];
    }
    __syncthreads();
    int idx = blockIdx.x * 256 + threadIdx.x;
    if (idx >= N) return;
    int bi = idx / (NJ * HWD);
    int rem = idx - bi * (NJ * HWD);
    int n = rem / HWD, p = rem % HWD;
    int h = p / WD, q = p % WD;
    float s0 = sqb[0], s1 = sqb[1];
    const float* ag = agg + (size_t)(idx - p) * 2;
#pragma unroll
    for (int k = 0; k < 9; ++k) {
        int hh = h + k / 3 - 1, qq = q + k % 3 - 1;
        if (hh < 0 || hh >= WD || qq < 0 || qq >= WD) continue;
        float2 v = *(const float2*)(ag + (hh * WD + qq) * 2);
        s0 += v.x * sqw[0 * 18 + 0 * 9 + k] + v.y * sqw[0 * 18 + 1 * 9 + k];
        s1 += v.x * sqw[1 * 18 + 0 * 9 + k] + v.y * sqw[1 * 18 + 1 * 9 + k];
    }
    float g0 = sigm(s0), g1 = sigm(s1);
    int xo = sel4(xoff, bi);
    const float* f = feats + ((size_t)(n + xo) * HWD + p) * CC;
    float acc[16];
#pragma unroll
    for (int o = 0; o < 16; ++o) acc[o] = b[o];
#pragma unroll
    for (int cg = 0; cg < 8; ++cg) {
        float4 v = *(const float4*)(f + cg * 4);
        const float* w0 = &wl[cg * 4 * 16];
#pragma unroll
        for (int o = 0; o < 16; ++o)
            acc[o] += v.x * w0[o] + v.y * w0[16 + o] + v.z * w0[32 + o] + v.w * w0[48 + o];
    }
    const float* ap = a1c + (size_t)rem * 16;
    unsigned* fp = (unsigned*)(fused + (size_t)idx * CC);
#pragma unroll
    for (int o = 0; o < 16; o += 2)
        fp[o >> 1] = pk2bf(ap[o] * g0, ap[o + 1] * g0);
#pragma unroll
    for (int o = 0; o < 16; o += 2)
        fp[8 + (o >> 1)] = pk2bf(acc[o] * g1, acc[o + 1] * g1);
}

// ---------------- cen_raw into aligned ch2 + arange output ----------------
__global__ void misc_k(const float* __restrict__ imgs, float* __restrict__ out) {
    int idx = blockIdx.x * 256 + threadIdx.x;
    float* alig = out + 135036 + 124;
    if (idx < NJ * HWD) {
        int n = idx / HWD, p = idx % HWD;
        alig[((size_t)n * 5 + 2) * HWD + p] = imgs[(size_t)(n + 2) * HWD + p];
    }
    if (idx < NJ) out[135036 + idx] = (float)(idx + 2);
}

extern "C" void kernel_launch(void* const* d_in, const int* in_sizes, int n_in,
                              void* d_out, int out_size, void* d_ws, size_t ws_size,
                              hipStream_t stream) {
    const float* x      = (const float*)d_in[0];
    const float* mlp_w  = (const float*)d_in[1];
    const float* mlp_b  = (const float*)d_in[2];
    const float* fe_w   = (const float*)d_in[3];
    const float* fe_b   = (const float*)d_in[4];
    const float* c0_w   = (const float*)d_in[5];
    const float* c0_b   = (const float*)d_in[6];
    const float* c1_w   = (const float*)d_in[7];
    const float* c1_b   = (const float*)d_in[8];
    const float* sq_w   = (const float*)d_in[9];
    const float* sq_b   = (const float*)d_in[10];
    const float* off1_w = (const float*)d_in[11];
    const float* off1_b = (const float*)d_in[12];
    const float* dw1    = (const float*)d_in[13];
    const float* off2_w = (const float*)d_in[14];
    const float* off2_b = (const float*)d_in[15];
    const float* dw2    = (const float*)d_in[16];
    const float* conv_w = (const float*)d_in[17];
    const float* conv_b = (const float*)d_in[18];
    const float* tc0_w  = (const float*)d_in[19];
    const float* tc0_b  = (const float*)d_in[20];
    const float* rb_w1  = (const float*)d_in[21];
    const float* rb_b1  = (const float*)d_in[22];
    const float* rb_w2  = (const float*)d_in[23];
    const float* rb_b2  = (const float*)d_in[24];
    const float* tail_w = (const float*)d_in[25];

    const size_t FRAME = (size_t)NJ * HWD;  // 135036

    const size_t baseB = ((size_t)1089 + NF * HWD + (size_t)NF * HWD * 32 + FRAME * 16) * 4 + 1024;
    const size_t perBB = FRAME * (2 * 4 + 32 * 2 + 18 * 4 + 32 * 2) + 512;
    int nb = 4;
    while (nb > 1 && baseB + (size_t)nb * perBB > ws_size) nb >>= 1;

    char* cur = (char*)d_ws;
    auto alloc = [&](size_t bytes) { char* p = cur; cur += (bytes + 63) & ~(size_t)63; return p; };
    float* rs    = (float*)alloc(1089 * 4);
    float* imgs  = (float*)alloc((size_t)NF * HWD * 4);
    float* feats = (float*)alloc((size_t)NF * HWD * 32 * 4);
    float* a1c   = (float*)alloc(FRAME * 16 * 4);
    float* agg   = (float*)alloc((size_t)nb * FRAME * 2 * 4);
    unsigned short* fused_bf = (unsigned short*)alloc((size_t)nb * FRAME * 32 * 2);
    float* offb  = (float*)alloc((size_t)nb * FRAME * 18 * 4);
    unsigned short* al1_bf = (unsigned short*)alloc((size_t)nb * FRAME * 32 * 2);

    float* hbuf = feats;
    unsigned short* hbuf_bf = (unsigned short*)a1c;
    unsigned short* tmp_bf  = fused_bf;
    unsigned short* al2_bf  = fused_bf;
    unsigned short* wpack = (unsigned short*)imgs;
    unsigned short* wp_off1 = wpack + 0 * 9216;
    unsigned short* wp_off2 = wpack + 1 * 9216;
    unsigned short* wp_dw1  = wpack + 12 * 9216;
    unsigned short* wp_dw2  = wpack + 13 * 9216;
    unsigned short* wp_cw   = wpack + 14 * 9216;

    float* outF = (float*)d_out;
    float* outA = outF + 135036 + 124;

    const int GF = (NF * HWD + 255) / 256;
    const int GJ = (NJ * HWD + 255) / 256;

    rowsum_k<<<HWD, 256, 0, stream>>>(mlp_w, rs);
    imgs_k<<<GF, 256, 0, stream>>>(x, rs, mlp_b, imgs);
    conv3x3_chwin<1, 32, true, false><<<GF, 256, 0, stream>>>(imgs, HWD, fe_w, fe_b, feats, nullptr, NF);
    misc_k<<<GJ, 256, 0, stream>>>(imgs, outF);
    pack_k<<<(15 * 9216 + 255) / 256, 256, 0, stream>>>(off1_w, off2_w, rb_w1, rb_w2, dw1, dw2, conv_w, wpack);
    a1c_k<<<GJ, 256, 0, stream>>>(feats, c0_w, c0_b, a1c);

    const int xoffs_all[4] = {0, 1, 3, 4};
    const int cidx_all[4]  = {0, 1, 3, 4};
    for (int pb = 0; pb < 4; pb += nb) {
        int4 xo = make_int4(xoffs_all[pb],
                            xoffs_all[(pb + 1) & 3],
                            xoffs_all[(pb + 2) & 3],
                            xoffs_all[(pb + 3) & 3]);
        int4 ci = make_int4(cidx_all[pb],
                            cidx_all[(pb + 1) & 3],
                            cidx_all[(pb + 2) & 3],
                            cidx_all[(pb + 3) & 3]);
        int4 f2 = make_int4(0, NJ, 2 * NJ, 3 * NJ);
        int N = nb * (int)FRAME;
        int GB = (N + 255) / 256;
        int GM = (N + 63) / 64;
        aggb_k<<<GB, 256, 0, stream>>>(feats, c1_w, c1_b, a1c, agg, xo, N);
        sigfusedb_k<<<GB, 256, 0, stream>>>(agg, sq_w, sq_b, a1c, feats, c1_w, c1_b, fused_bf, xo, N);
        mfmaconv_k<18, false, false, true, false><<<GM, 256, 0, stream>>>(
            fused_bf, wp_off1, off1_b, nullptr, offb, 18, nullptr, N);
        deform_lds_k<false, false, true><<<nb * NJ, 1024, 0, stream>>>(
            feats, offb, wp_dw1, nullptr, al1_bf, xo);
        mfmaconv_k<18, false, false, true, false><<<GM, 256, 0, stream>>>(
            al1_bf, wp_off2, off2_b, nullptr, offb, 18, nullptr, N);
        deform_lds_k<true, false, true><<<nb * NJ, 1024, 0, stream>>>(
            al1_bf, offb, wp_dw2, nullptr, al2_bf, f2);
        convout_mfma_k<<<GM, 256, 0, stream>>>(al2_bf, wp_cw, conv_b, outA, ci, N);
    }

    conv3x3_chwin<5, 32, true, true><<<GJ, 256, 0, stream>>>(
        outA, 5 * HWD, tc0_w, tc0_b, hbuf, hbuf_bf, NJ);
    const int GMF = ((int)FRAME + 63) / 64;
    for (int l = 0; l < 5; ++l) {
        mfmaconv_k<32, true, false, false, true><<<GMF, 256, 0, stream>>>(
            hbuf_bf, wpack + (size_t)(2 + l) * 9216, rb_b1 + l * CC, nullptr,
            nullptr, 0, tmp_bf, (int)FRAME);
        mfmaconv_k<32, false, true, true, true><<<GMF, 256, 0, stream>>>(
            tmp_bf, wpack + (size_t)(7 + l) * 9216, rb_b2 + l * CC, hbuf,
            hbuf, 32, hbuf_bf, (int)FRAME);
    }
    conv3x3_nhwc<32, 1, false, false, false><<<GJ, 256, 0, stream>>>(
        hbuf, tail_w, nullptr, nullptr, 0, 0, outF, 1, HWD, NJ);
}

// Round 19
// 608.215 us; speedup vs baseline: 1.2765x; 1.0015x over previous
//
#include <hip/hip_runtime.h>
#include <math.h>

#define HWD 1089
#define WD 33
#define NF 128
#define NJ 124
#define CC 32

typedef __attribute__((ext_vector_type(8))) short s16x8;
typedef __attribute__((ext_vector_type(4))) float f32x4;

__device__ __forceinline__ float sigm(float z) { return 1.f / (1.f + expf(-z)); }
__device__ __forceinline__ int sel4(int4 v, int i) { return i == 0 ? v.x : i == 1 ? v.y : i == 2 ? v.z : v.w; }
__device__ __forceinline__ short f2b(float f) {
    union { float f; unsigned u; } x; x.f = f;
    unsigned r = x.u + 0x7fffu + ((x.u >> 16) & 1u);
    return (short)(r >> 16);
}
__device__ __forceinline__ float b2f(unsigned short u) {
    union { unsigned u; float f; } x; x.u = (unsigned)u << 16;
    return x.f;
}
__device__ __forceinline__ unsigned pk2bf(float a, float b) {
    unsigned r;
    asm("v_cvt_pk_bf16_f32 %0, %1, %2" : "=v"(r) : "v"(a), "v"(b));
    return r;
}

// ---------------- rs[j] = sum_k mlp_w[j][k] ----------------
__global__ void rowsum_k(const float* __restrict__ mw, float* __restrict__ rs) {
    int j = blockIdx.x;
    const float* row = mw + (size_t)j * HWD;
    float s = 0.f;
    for (int k = threadIdx.x; k < HWD; k += 256) s += row[k];
    __shared__ float red[256];
    red[threadIdx.x] = s; __syncthreads();
    for (int off = 128; off > 0; off >>= 1) {
        if (threadIdx.x < off) red[threadIdx.x] += red[threadIdx.x + off];
        __syncthreads();
    }
    if (threadIdx.x == 0) rs[j] = red[0];
}

// ---------------- imgs = x * sigmoid((t/20)*rs + mlp_b) ----------------
__global__ void imgs_k(const float* __restrict__ x, const float* __restrict__ rs,
                       const float* __restrict__ mb, float* __restrict__ imgs) {
    int idx = blockIdx.x * 256 + threadIdx.x;
    if (idx >= NF * HWD) return;
    int t = idx / HWD, p = idx % HWD;
    float pe = sigm(((float)t / 20.0f) * rs[p] + mb[p]);
    imgs[idx] = x[idx] * pe;
}

// ---------------- weight pack: 15 tensors -> bf16 MFMA B-fragments ----------------
// t: 0=off1_w(18) 1=off2_w(18) 2..6=rb_w1[l](32) 7..11=rb_w2[l](32) 12=dw1(32) 13=dw2(32) 14=conv_w(1)
__global__ void pack_k(const float* __restrict__ off1_w, const float* __restrict__ off2_w,
                       const float* __restrict__ rb_w1, const float* __restrict__ rb_w2,
                       const float* __restrict__ dw1, const float* __restrict__ dw2,
                       const float* __restrict__ conv_w, unsigned short* __restrict__ wp) {
    int tid = blockIdx.x * 256 + threadIdx.x;
    if (tid >= 15 * 9216) return;
    int t = tid / 9216, u = tid - t * 9216;
    int j = u & 7, l = (u >> 3) & 63, h = (u >> 9) & 1, k = u >> 10;
    int o = h * 16 + (l & 15);
    int c = 8 * (l >> 4) + j;
    const float* src;
    int cout;
    if (t == 0)       { src = off1_w; cout = 18; }
    else if (t == 1)  { src = off2_w; cout = 18; }
    else if (t < 7)   { src = rb_w1 + (size_t)(t - 2) * 9216; cout = 32; }
    else if (t < 12)  { src = rb_w2 + (size_t)(t - 7) * 9216; cout = 32; }
    else if (t == 12) { src = dw1; cout = 32; }
    else if (t == 13) { src = dw2; cout = 32; }
    else              { src = conv_w; cout = 1; }
    float val = (o < cout) ? src[(o * 32 + c) * 9 + k] : 0.f;
    wp[tid] = (unsigned short)f2b(val);
}

// ---------------- MFMA 3x3 conv, bf16 NHWC input, COUT out, 9-tap prefetch ----------------
template <int COUT, bool RELU, bool HAS_RES, bool WF32, bool WBF>
__global__ __launch_bounds__(256, 2)
void mfmaconv_k(const unsigned short* __restrict__ in, const unsigned short* __restrict__ wp,
                const float* __restrict__ bias, const float* __restrict__ res,
                float* __restrict__ outf, int out_ps, unsigned short* __restrict__ outb_,
                int Npix) {
    int lane = threadIdx.x & 63;
    int wav  = threadIdx.x >> 6;
    int pix0 = (blockIdx.x * 4 + wav) * 16;
    if (pix0 >= Npix) return;
    s16x8 bf[18];
#pragma unroll
    for (int i = 0; i < 18; ++i)
        bf[i] = *(const s16x8*)(wp + ((size_t)(i * 64 + lane)) * 8);
    int am = lane & 15;
    int ak = lane >> 4;
    int apix = pix0 + am;
    bool aval = apix < Npix;
    int apixc = min(apix, Npix - 1);
    int ap = apixc % HWD;
    int ah = ap / WD, aq = ap - ah * WD;
    const unsigned short* abase = in + (size_t)apixc * 32 + ak * 8;
    s16x8 u[9];
    bool vm[9];
#pragma unroll
    for (int k = 0; k < 9; ++k) {
        int dy = k / 3 - 1, dx = k % 3 - 1;
        int hh = ah + dy, qq = aq + dx;
        vm[k] = aval && hh >= 0 && hh < WD && qq >= 0 && qq < WD;
        const unsigned short* ipp = vm[k] ? (abase + (dy * WD + dx) * 32) : abase;
        u[k] = *(const s16x8*)(ipp);
    }
    const s16x8 zz = {0, 0, 0, 0, 0, 0, 0, 0};
    f32x4 acc0 = {0.f, 0.f, 0.f, 0.f};
    f32x4 acc1 = {0.f, 0.f, 0.f, 0.f};
#pragma unroll
    for (int k = 0; k < 9; ++k) {
        s16x8 af = vm[k] ? u[k] : zz;
        acc0 = __builtin_amdgcn_mfma_f32_16x16x32_bf16(af, bf[k * 2 + 0], acc0, 0, 0, 0);
        acc1 = __builtin_amdgcn_mfma_f32_16x16x32_bf16(af, bf[k * 2 + 1], acc1, 0, 0, 0);
    }
    int n = lane & 15;
    int mrow = (lane >> 4) * 4;
    float b0 = bias[n];
    float b1 = (16 + n < COUT) ? bias[16 + n] : 0.f;
#pragma unroll
    for (int i = 0; i < 4; ++i) {
        int pix = pix0 + mrow + i;
        if (pix >= Npix) continue;
        float v0 = acc0[i] + b0;
        if (RELU) v0 = fmaxf(v0, 0.f);
        if (HAS_RES) v0 += res[(size_t)pix * 32 + n];
        if (WF32) outf[(size_t)pix * out_ps + n] = v0;
        if (WBF) outb_[(size_t)pix * 32 + n] = (unsigned short)f2b(v0);
        if (16 + n < COUT) {
            float v1 = acc1[i] + b1;
            if (RELU) v1 = fmaxf(v1, 0.f);
            if (HAS_RES) v1 += res[(size_t)pix * 32 + 16 + n];
            if (WF32) outf[(size_t)pix * out_ps + 16 + n] = v1;
            if (WBF) outb_[(size_t)pix * 32 + 16 + n] = (unsigned short)f2b(v1);
        }
    }
}

// ---------------- MFMA 3x3 conv 32->1 (bf16 in) -> aligned NCHW channel ----------------
__global__ __launch_bounds__(256, 2)
void convout_mfma_k(const unsigned short* __restrict__ in, const unsigned short* __restrict__ wp,
                    const float* __restrict__ cb, float* __restrict__ outA, int4 cidx, int Npix) {
    int lane = threadIdx.x & 63;
    int wav  = threadIdx.x >> 6;
    int pix0 = (blockIdx.x * 4 + wav) * 16;
    if (pix0 >= Npix) return;
    s16x8 bc[9];
#pragma unroll
    for (int k = 0; k < 9; ++k)
        bc[k] = *(const s16x8*)(wp + ((size_t)((k * 2 + 0) * 64 + lane)) * 8);
    int am = lane & 15, ak = lane >> 4;
    int apix = pix0 + am;
    bool aval = apix < Npix;
    int apixc = min(apix, Npix - 1);
    int ap = apixc % HWD;
    int ah = ap / WD, aq = ap - ah * WD;
    const unsigned short* abase = in + (size_t)apixc * 32 + ak * 8;
    s16x8 u[9];
    bool vm[9];
#pragma unroll
    for (int k = 0; k < 9; ++k) {
        int dy = k / 3 - 1, dx = k % 3 - 1;
        int hh = ah + dy, qq = aq + dx;
        vm[k] = aval && hh >= 0 && hh < WD && qq >= 0 && qq < WD;
        const unsigned short* ipp = vm[k] ? (abase + (dy * WD + dx) * 32) : abase;
        u[k] = *(const s16x8*)(ipp);
    }
    const s16x8 zz = {0, 0, 0, 0, 0, 0, 0, 0};
    f32x4 acc = {0.f, 0.f, 0.f, 0.f};
#pragma unroll
    for (int k = 0; k < 9; ++k)
        acc = __builtin_amdgcn_mfma_f32_16x16x32_bf16(vm[k] ? u[k] : zz, bc[k], acc, 0, 0, 0);
    if ((lane & 15) == 0) {
        float b0 = cb[0];
        int mrow = (lane >> 4) * 4;
#pragma unroll
        for (int i = 0; i < 4; ++i) {
            int pix = pix0 + mrow + i;
            if (pix >= Npix) continue;
            int bi = pix / (NJ * HWD);
            int rem = pix - bi * (NJ * HWD);
            int n = rem / HWD, p = rem - n * HWD;
            outA[((size_t)n * 5 + sel4(cidx, bi)) * HWD + p] = acc[i] + b0;
        }
    }
}

// ---------------- LDS-staged MFMA deformable conv: f32 LDS stride 36 floats, 16 waves ----------------
template <bool INBF, bool OUTF32, bool OUTBF>
__global__ __launch_bounds__(1024, 1)
void deform_lds_k(const void* __restrict__ base_, const float* __restrict__ off,
                  const unsigned short* __restrict__ wp, float* __restrict__ outf,
                  unsigned short* __restrict__ outb_, int4 froff) {
    __shared__ float sf[HWD * 36];  // 156,816 B
    int b = blockIdx.x;
    int bi = b / NJ, n = b - bi * NJ;
    if (INBF) {
        const unsigned short* xf = (const unsigned short*)base_ + (size_t)(n + sel4(froff, bi)) * HWD * 32;
        for (int i = threadIdx.x; i < HWD * 4; i += 1024) {
            int p = i >> 2, cg = i & 3;
            s16x8 v = *(const s16x8*)(xf + p * 32 + cg * 8);
            float4 f0 = make_float4(b2f((unsigned short)v[0]), b2f((unsigned short)v[1]),
                                    b2f((unsigned short)v[2]), b2f((unsigned short)v[3]));
            float4 f1 = make_float4(b2f((unsigned short)v[4]), b2f((unsigned short)v[5]),
                                    b2f((unsigned short)v[6]), b2f((unsigned short)v[7]));
            *(float4*)(sf + p * 36 + cg * 8) = f0;
            *(float4*)(sf + p * 36 + cg * 8 + 4) = f1;
        }
    } else {
        const float* xf = (const float*)base_ + (size_t)(n + sel4(froff, bi)) * HWD * CC;
        for (int i = threadIdx.x; i < HWD * 8; i += 1024) {
            int p = i >> 3, cg = i & 7;
            *(float4*)(sf + p * 36 + cg * 4) = *(const float4*)(xf + p * 32 + cg * 4);
        }
    }
    int lane = threadIdx.x & 63;
    int wav  = threadIdx.x >> 6;
    s16x8 bf[18];
#pragma unroll
    for (int i = 0; i < 18; ++i)
        bf[i] = *(const s16x8*)(wp + ((size_t)(i * 64 + lane)) * 8);
    __syncthreads();
    int am = lane & 15, kg = lane >> 4;
    const float* offb = off + (size_t)b * HWD * 18;
    size_t outbase = (size_t)b * HWD * 32;
    for (int tile = wav; tile * 16 < HWD; tile += 16) {
        int pix0 = tile * 16;
        int p = min(pix0 + am, HWD - 1);
        int h = p / WD, q = p - h * WD;
        const float* ofp = offb + (size_t)p * 18;
        float2 dv[9];
#pragma unroll
        for (int kk = 0; kk < 9; ++kk) dv[kk] = *(const float2*)(ofp + 2 * kk);
        f32x4 acc0 = {0.f, 0.f, 0.f, 0.f};
        f32x4 acc1 = {0.f, 0.f, 0.f, 0.f};
#pragma unroll
        for (int kk = 0; kk < 9; ++kk) {
            int ky = kk / 3, kx = kk - ky * 3;
            float py = (float)(h - 1 + ky) + dv[kk].x;
            float px = (float)(q - 1 + kx) + dv[kk].y;
            float y0f = floorf(py), x0f = floorf(px);
            float ly = py - y0f, lx = px - x0f;
            int y0 = (int)y0f, x0 = (int)x0f;
            float w00 = (1.f - ly) * (1.f - lx), w01 = (1.f - ly) * lx;
            float w10 = ly * (1.f - lx), w11 = ly * lx;
            bool yv0 = (y0 >= 0 && y0 < WD), yv1 = (y0 + 1 >= 0 && y0 + 1 < WD);
            bool xv0 = (x0 >= 0 && x0 < WD), xv1 = (x0 + 1 >= 0 && x0 + 1 < WD);
            if (!(yv0 && xv0)) w00 = 0.f;
            if (!(yv0 && xv1)) w01 = 0.f;
            if (!(yv1 && xv0)) w10 = 0.f;
            if (!(yv1 && xv1)) w11 = 0.f;
            int yc0 = min(max(y0, 0), WD - 1), yc1 = min(max(y0 + 1, 0), WD - 1);
            int xc0 = min(max(x0, 0), WD - 1), xc1 = min(max(x0 + 1, 0), WD - 1);
            const float* s00 = sf + (yc0 * WD + xc0) * 36 + kg * 8;
            const float* s01 = sf + (yc0 * WD + xc1) * 36 + kg * 8;
            const float* s10 = sf + (yc1 * WD + xc0) * 36 + kg * 8;
            const float* s11 = sf + (yc1 * WD + xc1) * 36 + kg * 8;
            float4 a0 = *(const float4*)(s00);
            float4 a1 = *(const float4*)(s00 + 4);
            float4 b0 = *(const float4*)(s01);
            float4 b1 = *(const float4*)(s01 + 4);
            float4 c0 = *(const float4*)(s10);
            float4 c1 = *(const float4*)(s10 + 4);
            float4 d0 = *(const float4*)(s11);
            float4 d1 = *(const float4*)(s11 + 4);
            float v0 = a0.x * w00 + b0.x * w01 + c0.x * w10 + d0.x * w11;
            float v1 = a0.y * w00 + b0.y * w01 + c0.y * w10 + d0.y * w11;
            float v2 = a0.z * w00 + b0.z * w01 + c0.z * w10 + d0.z * w11;
            float v3 = a0.w * w00 + b0.w * w01 + c0.w * w10 + d0.w * w11;
            float v4 = a1.x * w00 + b1.x * w01 + c1.x * w10 + d1.x * w11;
            float v5 = a1.y * w00 + b1.y * w01 + c1.y * w10 + d1.y * w11;
            float v6 = a1.z * w00 + b1.z * w01 + c1.z * w10 + d1.z * w11;
            float v7 = a1.w * w00 + b1.w * w01 + c1.w * w10 + d1.w * w11;
            union { s16x8 v; unsigned u[4]; } af;
            af.u[0] = pk2bf(v0, v1);
            af.u[1] = pk2bf(v2, v3);
            af.u[2] = pk2bf(v4, v5);
            af.u[3] = pk2bf(v6, v7);
            acc0 = __builtin_amdgcn_mfma_f32_16x16x32_bf16(af.v, bf[kk * 2 + 0], acc0, 0, 0, 0);
            acc1 = __builtin_amdgcn_mfma_f32_16x16x32_bf16(af.v, bf[kk * 2 + 1], acc1, 0, 0, 0);
        }
        int nn = lane & 15;
        int mrow = (lane >> 4) * 4;
#pragma unroll
        for (int i = 0; i < 4; ++i) {
            int pix = pix0 + mrow + i;
            if (pix >= HWD) continue;
            if (OUTF32) {
                outf[outbase + (size_t)pix * 32 + nn]      = acc0[i];
                outf[outbase + (size_t)pix * 32 + 16 + nn] = acc1[i];
            }
            if (OUTBF) {
                outb_[outbase + (size_t)pix * 32 + nn]      = (unsigned short)f2b(acc0[i]);
                outb_[outbase + (size_t)pix * 32 + 16 + nn] = (unsigned short)f2b(acc1[i]);
            }
        }
    }
}

// ---------------- 3x3 conv NHWC f32 (1 px/thread) — tail ----------------
template <int CIN, int COUT, bool RELU, bool HAS_B, bool HAS_RES>
__global__ __launch_bounds__(256, 2)
void conv3x3_nhwc(const float* __restrict__ in,
                  const float* __restrict__ w, const float* __restrict__ b,
                  const float* __restrict__ res, int res_ps, int res_ns,
                  float* __restrict__ out, int out_ps, int out_ns, int N) {
    constexpr int WROW = (COUT + 3) & ~3;
    __shared__ float wl[9 * CIN * WROW];
    for (int i = threadIdx.x; i < 9 * CIN * WROW; i += 256) {
        int o = i % WROW, r = i / WROW;
        int c = r % CIN, k = r / CIN;
        wl[i] = (o < COUT) ? w[(o * CIN + c) * 9 + k] : 0.f;
    }
    __syncthreads();
    int idx = blockIdx.x * 256 + threadIdx.x;
    if (idx >= N * HWD) return;
    int n = idx / HWD, p = idx % HWD;
    int h = p / WD, q = p % WD;
    float acc[COUT];
#pragma unroll
    for (int o = 0; o < COUT; ++o) acc[o] = HAS_B ? b[o] : 0.f;
    const float* inn = in + (size_t)n * HWD * CIN;
#pragma unroll
    for (int k = 0; k < 9; ++k) {
        int hh = h + k / 3 - 1, qq = q + k % 3 - 1;
        if (hh < 0 || hh >= WD || qq < 0 || qq >= WD) continue;
        const float* ip = inn + (hh * WD + qq) * CIN;
        const float* wk = &wl[k * CIN * WROW];
#pragma unroll
        for (int cg = 0; cg < CIN / 4; ++cg) {
            float4 v = *(const float4*)(ip + cg * 4);
            const float* w0 = wk + (cg * 4) * WROW;
#pragma unroll
            for (int o = 0; o < COUT; ++o)
                acc[o] += v.x * w0[o] + v.y * w0[WROW + o]
                        + v.z * w0[2 * WROW + o] + v.w * w0[3 * WROW + o];
        }
    }
#pragma unroll
    for (int o = 0; o < COUT; ++o) {
        float val = acc[o];
        if (RELU) val = fmaxf(val, 0.f);
        if (HAS_RES) val += res[(size_t)n * res_ns + (size_t)p * res_ps + o];
        out[(size_t)n * out_ns + (size_t)p * out_ps + o] = val;
    }
}

// ---------------- 3x3 conv, CHW input, NHWC f32 out (+optional bf16 copy) ----------------
template <int CIN, int COUT, bool RELU, bool WBF>
__global__ __launch_bounds__(256, 2)
void conv3x3_chwin(const float* __restrict__ in, int in_ns,
                   const float* __restrict__ w, const float* __restrict__ b,
                   float* __restrict__ out, unsigned short* __restrict__ out_bf, int N) {
    __shared__ float wl[CIN * 9 * COUT];
    for (int i = threadIdx.x; i < CIN * 9 * COUT; i += 256) {
        int o = i % COUT, r = i / COUT;
        int k = r % 9, c = r / 9;
        wl[i] = w[(o * CIN + c) * 9 + k];
    }
    __syncthreads();
    int idx = blockIdx.x * 256 + threadIdx.x;
    if (idx >= N * HWD) return;
    int n = idx / HWD, p = idx % HWD;
    int h = p / WD, q = p % WD;
    float acc[COUT];
#pragma unroll
    for (int o = 0; o < COUT; ++o) acc[o] = b[o];
    const float* inn = in + (size_t)n * in_ns;
#pragma unroll
    for (int c = 0; c < CIN; ++c) {
#pragma unroll
        for (int k = 0; k < 9; ++k) {
            int hh = h + k / 3 - 1, qq = q + k % 3 - 1;
            if (hh < 0 || hh >= WD || qq < 0 || qq >= WD) continue;
            float v = inn[c * HWD + hh * WD + qq];
            const float* wp = &wl[(c * 9 + k) * COUT];
#pragma unroll
            for (int o = 0; o < COUT; ++o) acc[o] += v * wp[o];
        }
    }
    float* op = out + ((size_t)idx) * COUT;
#pragma unroll
    for (int o = 0; o < COUT; ++o) {
        float r = RELU ? fmaxf(acc[o], 0.f) : acc[o];
        acc[o] = r;
        op[o] = r;
    }
    if (WBF) {
        unsigned* ob = (unsigned*)(out_bf + (size_t)idx * COUT);
#pragma unroll
        for (int o = 0; o < COUT; o += 2) ob[o >> 1] = pk2bf(acc[o], acc[o + 1]);
    }
}

// ---------------- a1c = 1x1 conv (16 out) of feats[n+2], NHWC ----------------
__global__ void a1c_k(const float* __restrict__ feats, const float* __restrict__ w,
                      const float* __restrict__ b, float* __restrict__ a1c) {
    __shared__ float wl[CC * 16];
    for (int i = threadIdx.x; i < CC * 16; i += 256) {
        int o = i % 16, c = i / 16;
        wl[i] = w[o * CC + c];
    }
    __syncthreads();
    int idx = blockIdx.x * 256 + threadIdx.x;
    if (idx >= NJ * HWD) return;
    int n = idx / HWD, p = idx % HWD;
    const float* f = feats + ((size_t)(n + 2) * HWD + p) * CC;
    float acc[16];
#pragma unroll
    for (int o = 0; o < 16; ++o) acc[o] = b[o];
#pragma unroll
    for (int cg = 0; cg < 8; ++cg) {
        float4 v = *(const float4*)(f + cg * 4);
        const float* w0 = &wl[cg * 4 * 16];
#pragma unroll
        for (int o = 0; o < 16; ++o)
            acc[o] += v.x * w0[o] + v.y * w0[16 + o] + v.z * w0[32 + o] + v.w * w0[48 + o];
    }
    float* op = a1c + (size_t)idx * 16;
#pragma unroll
    for (int o = 0; o < 16; o += 4)
        *(float4*)(op + o) = make_float4(acc[o], acc[o+1], acc[o+2], acc[o+3]);
}

// ---------------- batched: a2 (recomputed) + agg=[mean,max] ----------------
__global__ void aggb_k(const float* __restrict__ feats, const float* __restrict__ w,
                       const float* __restrict__ b, const float* __restrict__ a1c,
                       float* __restrict__ agg, int4 xoff, int N) {
    __shared__ float wl[CC * 16];
    for (int i = threadIdx.x; i < CC * 16; i += 256) {
        int o = i % 16, c = i / 16;
        wl[i] = w[o * CC + c];
    }
    __syncthreads();
    int idx = blockIdx.x * 256 + threadIdx.x;
    if (idx >= N) return;
    int bi = idx / (NJ * HWD);
    int rem = idx - bi * (NJ * HWD);
    int n = rem / HWD, p = rem % HWD;
    int xo = sel4(xoff, bi);
    const float* f = feats + ((size_t)(n + xo) * HWD + p) * CC;
    float acc[16];
#pragma unroll
    for (int o = 0; o < 16; ++o) acc[o] = b[o];
#pragma unroll
    for (int cg = 0; cg < 8; ++cg) {
        float4 v = *(const float4*)(f + cg * 4);
        const float* w0 = &wl[cg * 4 * 16];
#pragma unroll
        for (int o = 0; o < 16; ++o)
            acc[o] += v.x * w0[o] + v.y * w0[16 + o] + v.z * w0[32 + o] + v.w * w0[48 + o];
    }
    float sum = 0.f, mx = -1e30f;
    const float* ap = a1c + (size_t)rem * 16;
#pragma unroll
    for (int o = 0; o < 16; ++o) {
        float v = ap[o];
        sum += v; mx = fmaxf(mx, v);
    }
#pragma unroll
    for (int o = 0; o < 16; ++o) {
        sum += acc[o]; mx = fmaxf(mx, acc[o]);
    }
    agg[(size_t)idx * 2 + 0] = sum * (1.f / 32.f);
    agg[(size_t)idx * 2 + 1] = mx;
}

// ---------------- batched: sig; fused(bf16) = [a1c*g0, a2*g1] ----------------
__global__ void sigfusedb_k(const float* __restrict__ agg, const float* __restrict__ sqw,
                            const float* __restrict__ sqb, const float* __restrict__ a1c,
                            const float* __restrict__ feats, const float* __restrict__ w,
                            const float* __restrict__ b, unsigned short* __restrict__ fused,
                            int4 xoff, int N) {
    __shared__ float wl[CC * 16];
    for (int i = threadIdx.x; i < CC * 16; i += 256) {
        int o = i % 16, c = i / 16;
        wl[i] = w[o * CC + c];
    }
    __syncthreads();
    int idx = blockIdx.x * 256 + threadIdx.x;
    if (idx >= N) return;
    int bi = idx / (NJ * HWD);
    int rem = idx - bi * (NJ * HWD);
    int n = rem / HWD, p = rem % HWD;
    int h = p / WD, q = p % WD;
    float s0 = sqb[0], s1 = sqb[1];
    const float* ag = agg + (size_t)(idx - p) * 2;
#pragma unroll
    for (int k = 0; k < 9; ++k) {
        int hh = h + k / 3 - 1, qq = q + k % 3 - 1;
        if (hh < 0 || hh >= WD || qq < 0 || qq >= WD) continue;
        float2 v = *(const float2*)(ag + (hh * WD + qq) * 2);
        s0 += v.x * sqw[0 * 18 + 0 * 9 + k] + v.y * sqw[0 * 18 + 1 * 9 + k];
        s1 += v.x * sqw[1 * 18 + 0 * 9 + k] + v.y * sqw[1 * 18 + 1 * 9 + k];
    }
    float g0 = sigm(s0), g1 = sigm(s1);
    int xo = sel4(xoff, bi);
    const float* f = feats + ((size_t)(n + xo) * HWD + p) * CC;
    float acc[16];
#pragma unroll
    for (int o = 0; o < 16; ++o) acc[o] = b[o];
#pragma unroll
    for (int cg = 0; cg < 8; ++cg) {
        float4 v = *(const float4*)(f + cg * 4);
        const float* w0 = &wl[cg * 4 * 16];
#pragma unroll
        for (int o = 0; o < 16; ++o)
            acc[o] += v.x * w0[o] + v.y * w0[16 + o] + v.z * w0[32 + o] + v.w * w0[48 + o];
    }
    const float* ap = a1c + (size_t)rem * 16;
    unsigned* fp = (unsigned*)(fused + (size_t)idx * CC);
#pragma unroll
    for (int o = 0; o < 16; o += 2)
        fp[o >> 1] = pk2bf(ap[o] * g0, ap[o + 1] * g0);
#pragma unroll
    for (int o = 0; o < 16; o += 2)
        fp[8 + (o >> 1)] = pk2bf(acc[o] * g1, acc[o + 1] * g1);
}

// ---------------- cen_raw into aligned ch2 + arange output ----------------
__global__ void misc_k(const float* __restrict__ imgs, float* __restrict__ out) {
    int idx = blockIdx.x * 256 + threadIdx.x;
    float* alig = out + 135036 + 124;
    if (idx < NJ * HWD) {
        int n = idx / HWD, p = idx % HWD;
        alig[((size_t)n * 5 + 2) * HWD + p] = imgs[(size_t)(n + 2) * HWD + p];
    }
    if (idx < NJ) out[135036 + idx] = (float)(idx + 2);
}

extern "C" void kernel_launch(void* const* d_in, const int* in_sizes, int n_in,
                              void* d_out, int out_size, void* d_ws, size_t ws_size,
                              hipStream_t stream) {
    const float* x      = (const float*)d_in[0];
    const float* mlp_w  = (const float*)d_in[1];
    const float* mlp_b  = (const float*)d_in[2];
    const float* fe_w   = (const float*)d_in[3];
    const float* fe_b   = (const float*)d_in[4];
    const float* c0_w   = (const float*)d_in[5];
    const float* c0_b   = (const float*)d_in[6];
    const float* c1_w   = (const float*)d_in[7];
    const float* c1_b   = (const float*)d_in[8];
    const float* sq_w   = (const float*)d_in[9];
    const float* sq_b   = (const float*)d_in[10];
    const float* off1_w = (const float*)d_in[11];
    const float* off1_b = (const float*)d_in[12];
    const float* dw1    = (const float*)d_in[13];
    const float* off2_w = (const float*)d_in[14];
    const float* off2_b = (const float*)d_in[15];
    const float* dw2    = (const float*)d_in[16];
    const float* conv_w = (const float*)d_in[17];
    const float* conv_b = (const float*)d_in[18];
    const float* tc0_w  = (const float*)d_in[19];
    const float* tc0_b  = (const float*)d_in[20];
    const float* rb_w1  = (const float*)d_in[21];
    const float* rb_b1  = (const float*)d_in[22];
    const float* rb_w2  = (const float*)d_in[23];
    const float* rb_b2  = (const float*)d_in[24];
    const float* tail_w = (const float*)d_in[25];

    const size_t FRAME = (size_t)NJ * HWD;  // 135036

    const size_t baseB = ((size_t)1089 + NF * HWD + (size_t)NF * HWD * 32 + FRAME * 16) * 4 + 1024;
    const size_t perBB = FRAME * (2 * 4 + 32 * 2 + 18 * 4 + 32 * 2) + 512;
    int nb = 4;
    while (nb > 1 && baseB + (size_t)nb * perBB > ws_size) nb >>= 1;

    char* cur = (char*)d_ws;
    auto alloc = [&](size_t bytes) { char* p = cur; cur += (bytes + 63) & ~(size_t)63; return p; };
    float* rs    = (float*)alloc(1089 * 4);
    float* imgs  = (float*)alloc((size_t)NF * HWD * 4);
    float* feats = (float*)alloc((size_t)NF * HWD * 32 * 4);
    float* a1c   = (float*)alloc(FRAME * 16 * 4);
    float* agg   = (float*)alloc((size_t)nb * FRAME * 2 * 4);
    unsigned short* fused_bf = (unsigned short*)alloc((size_t)nb * FRAME * 32 * 2);
    float* offb  = (float*)alloc((size_t)nb * FRAME * 18 * 4);
    unsigned short* al1_bf = (unsigned short*)alloc((size_t)nb * FRAME * 32 * 2);

    float* hbuf = feats;
    unsigned short* hbuf_bf = (unsigned short*)a1c;
    unsigned short* tmp_bf  = fused_bf;
    unsigned short* al2_bf  = fused_bf;
    unsigned short* wpack = (unsigned short*)imgs;
    unsigned short* wp_off1 = wpack + 0 * 9216;
    unsigned short* wp_off2 = wpack + 1 * 9216;
    unsigned short* wp_dw1  = wpack + 12 * 9216;
    unsigned short* wp_dw2  = wpack + 13 * 9216;
    unsigned short* wp_cw   = wpack + 14 * 9216;

    float* outF = (float*)d_out;
    float* outA = outF + 135036 + 124;

    const int GF = (NF * HWD + 255) / 256;
    const int GJ = (NJ * HWD + 255) / 256;

    rowsum_k<<<HWD, 256, 0, stream>>>(mlp_w, rs);
    imgs_k<<<GF, 256, 0, stream>>>(x, rs, mlp_b, imgs);
    conv3x3_chwin<1, 32, true, false><<<GF, 256, 0, stream>>>(imgs, HWD, fe_w, fe_b, feats, nullptr, NF);
    misc_k<<<GJ, 256, 0, stream>>>(imgs, outF);
    pack_k<<<(15 * 9216 + 255) / 256, 256, 0, stream>>>(off1_w, off2_w, rb_w1, rb_w2, dw1, dw2, conv_w, wpack);
    a1c_k<<<GJ, 256, 0, stream>>>(feats, c0_w, c0_b, a1c);

    const int xoffs_all[4] = {0, 1, 3, 4};
    const int cidx_all[4]  = {0, 1, 3, 4};
    for (int pb = 0; pb < 4; pb += nb) {
        int4 xo = make_int4(xoffs_all[pb],
                            xoffs_all[(pb + 1) & 3],
                            xoffs_all[(pb + 2) & 3],
                            xoffs_all[(pb + 3) & 3]);
        int4 ci = make_int4(cidx_all[pb],
                            cidx_all[(pb + 1) & 3],
                            cidx_all[(pb + 2) & 3],
                            cidx_all[(pb + 3) & 3]);
        int4 f2 = make_int4(0, NJ, 2 * NJ, 3 * NJ);
        int N = nb * (int)FRAME;
        int GB = (N + 255) / 256;
        int GM = (N + 63) / 64;
        aggb_k<<<GB, 256, 0, stream>>>(feats, c1_w, c1_b, a1c, agg, xo, N);
        sigfusedb_k<<<GB, 256, 0, stream>>>(agg, sq_w, sq_b, a1c, feats, c1_w, c1_b, fused_bf, xo, N);
        mfmaconv_k<18, false, false, true, false><<<GM, 256, 0, stream>>>(
            fused_bf, wp_off1, off1_b, nullptr, offb, 18, nullptr, N);
        deform_lds_k<false, false, true><<<nb * NJ, 1024, 0, stream>>>(
            feats, offb, wp_dw1, nullptr, al1_bf, xo);
        mfmaconv_k<18, false, false, true, false><<<GM, 256, 0, stream>>>(
            al1_bf, wp_off2, off2_b, nullptr, offb, 18, nullptr, N);
        deform_lds_k<true, false, true><<<nb * NJ, 1024, 0, stream>>>(
            al1_bf, offb, wp_dw2, nullptr, al2_bf, f2);
        convout_mfma_k<<<GM, 256, 0, stream>>>(al2_bf, wp_cw, conv_b, outA, ci, N);
    }

    conv3x3_chwin<5, 32, true, true><<<GJ, 256, 0, stream>>>(
        outA, 5 * HWD, tc0_w, tc0_b, hbuf, hbuf_bf, NJ);
    const int GMF = ((int)FRAME + 63) / 64;
    for (int l = 0; l < 5; ++l) {
        mfmaconv_k<32, true, false, false, true><<<GMF, 256, 0, stream>>>(
            hbuf_bf, wpack + (size_t)(2 + l) * 9216, rb_b1 + l * CC, nullptr,
            nullptr, 0, tmp_bf, (int)FRAME);
        mfmaconv_k<32, false, true, true, true><<<GMF, 256, 0, stream>>>(
            tmp_bf, wpack + (size_t)(7 + l) * 9216, rb_b2 + l * CC, hbuf,
            hbuf, 32, hbuf_bf, (int)FRAME);
    }
    conv3x3_nhwc<32, 1, false, false, false><<<GJ, 256, 0, stream>>>(
        hbuf, tail_w, nullptr, nullptr, 0, 0, outF, 1, HWD, NJ);
}